// Round 1
// 906.140 us; speedup vs baseline: 1.0292x; 1.0292x over previous
//
#include <hip/hip_runtime.h>

typedef _Float16 half8 __attribute__((ext_vector_type(8)));
typedef float    floatx4 __attribute__((ext_vector_type(4)));
typedef unsigned short u16;

constexpr int Bn  = 8;
constexpr int Sq  = 2048;   // S1 == S2
constexpr int KD  = 512;    // K1_DIM == K2_DIM
constexpr int PKD = 256;
constexpr int AD  = 512;    // ATT_DIM
constexpr int DV  = 512;

// 16-byte async global->LDS DMA. LDS dest must be wave-uniform base + lane*16.
__device__ __forceinline__ void llds16(const void* g, void* l)
{
    __builtin_amdgcn_global_load_lds(
        (const __attribute__((address_space(1))) unsigned int*)g,
        (__attribute__((address_space(3))) unsigned int*)l, 16, 0, 0);
}

// ---------------------------------------------------------------------------
// transpose + cast f32 -> f16:  out[j][i] = (f16) in[i][j]
// ---------------------------------------------------------------------------
__global__ __launch_bounds__(256)
void transpose_cast_k(const float* __restrict__ in, _Float16* __restrict__ out,
                      int inRows, int inCols, long long bsIn, long long bsOut)
{
    __shared__ float t[32][33];
    const int b = blockIdx.z;
    in  += (long long)b * bsIn;
    out += (long long)b * bsOut;
    const int tx = threadIdx.x & 31;
    const int ty = threadIdx.x >> 5;     // 0..7
    const int c0 = blockIdx.x * 32;
    const int r0 = blockIdx.y * 32;
#pragma unroll
    for (int i = 0; i < 4; ++i)
        t[ty + 8*i][tx] = in[(long long)(r0 + ty + 8*i) * inCols + c0 + tx];
    __syncthreads();
#pragma unroll
    for (int i = 0; i < 4; ++i)
        out[(long long)(c0 + ty + 8*i) * inRows + r0 + tx] = (_Float16)t[tx][ty + 8*i];
}

// ---------------------------------------------------------------------------
// 128x128x32 fp16 MFMA GEMM, m97-style global_load_lds staging.
// C[M][N] = A[M][K] * B^T   (B stored [N][K] f16, k-contiguous)
// ---------------------------------------------------------------------------
template<bool A_F32, bool OUT_F16>
__global__ __launch_bounds__(256, 2)
void gemm_k(const void* __restrict__ A1v, const void* __restrict__ A2v, int Ksplit,
            int lda1, int lda2, long long bsA,
            const _Float16* __restrict__ Bm, int ldb, long long bsB,
            void* __restrict__ Cv, int ldc, long long bsC,
            const float* __restrict__ bias, int K)
{
    __shared__ __align__(16) unsigned char AsRaw[A_F32 ? 16384 : 8192]; // 128x32
    __shared__ __align__(16) unsigned char BsRaw[8192];                 // 128x32 f16

    const int tid  = threadIdx.x;
    const int lane = tid & 63;
    const int wave = tid >> 6;
    const int wm   = (wave >> 1) * 64;
    const int wn   = (wave & 1) * 64;
    const int fr   = lane & 15;       // frag row (A) / col (B,D)
    const int fq   = lane >> 4;       // quad: k-offset fq*8, D-row fq*4

    const int tm = blockIdx.y, tn = blockIdx.x, bz = blockIdx.z;
    const long long aRowBase = (long long)tm * 128;
    const long long bRowBase = (long long)tn * 128;
    const _Float16* Bbase = Bm + (long long)bz * bsB;

    floatx4 acc[4][4];
#pragma unroll
    for (int i = 0; i < 4; ++i)
#pragma unroll
        for (int j = 0; j < 4; ++j) acc[i][j] = (floatx4)0.0f;

    for (int k0 = 0; k0 < K; k0 += 32) {
        __syncthreads();   // previous tile's ds_reads complete before overwrite

        if (A_F32) {
            const float* A1 = (const float*)A1v + (long long)bz * bsA;
            const float* A2 = (const float*)A2v;
#pragma unroll
            for (int is = 0; is < 4; ++is) {
                const int r  = (tid >> 3) + is * 32;       // 0..127
                const int ch = (tid & 7) ^ (r & 7);        // swizzled 16B chunk
                const int kk = k0 + ch * 4;                // f32 col
                const float* src = (kk < Ksplit)
                    ? A1 + (aRowBase + r) * lda1 + kk
                    : A2 + (aRowBase + r) * lda2 + (kk - Ksplit);
                llds16(src, AsRaw + tid * 16 + is * 4096);
            }
        } else {
            const _Float16* A1 = (const _Float16*)A1v + (long long)bz * bsA;
#pragma unroll
            for (int is = 0; is < 2; ++is) {
                const int r  = (tid >> 2) + is * 64;       // 0..127
                const int ch = (tid & 3) ^ (r & 3);
                llds16(A1 + (aRowBase + r) * lda1 + k0 + ch * 8,
                       AsRaw + tid * 16 + is * 4096);
            }
        }
#pragma unroll
        for (int is = 0; is < 2; ++is) {
            const int r  = (tid >> 2) + is * 64;
            const int ch = (tid & 3) ^ (r & 3);
            llds16(Bbase + (bRowBase + r) * ldb + k0 + ch * 8,
                   BsRaw + tid * 16 + is * 4096);
        }

        __syncthreads();   // drains vmcnt(0): DMA visible to all waves

        half8 af[4], bf[4];
        if (A_F32) {
            const float* As32 = (const float*)AsRaw;
#pragma unroll
            for (int i = 0; i < 4; ++i) {
                const int r  = wm + i * 16 + fr;
                const int c0 = ((2 * fq) ^ (r & 7)) * 4;
                const int c1 = ((2 * fq + 1) ^ (r & 7)) * 4;
                floatx4 f0 = *(const floatx4*)(As32 + r * 32 + c0);
                floatx4 f1 = *(const floatx4*)(As32 + r * 32 + c1);
                half8 h;
#pragma unroll
                for (int j = 0; j < 4; ++j) {
                    h[j]     = (_Float16)f0[j];
                    h[4 + j] = (_Float16)f1[j];
                }
                af[i] = h;
            }
        } else {
            const _Float16* As16 = (const _Float16*)AsRaw;
#pragma unroll
            for (int i = 0; i < 4; ++i) {
                const int r  = wm + i * 16 + fr;
                const int ch = fq ^ (r & 3);
                af[i] = *(const half8*)(As16 + r * 32 + ch * 8);
            }
        }
        {
            const _Float16* Bs16 = (const _Float16*)BsRaw;
#pragma unroll
            for (int j = 0; j < 4; ++j) {
                const int r  = wn + j * 16 + fr;
                const int ch = fq ^ (r & 3);
                bf[j] = *(const half8*)(Bs16 + r * 32 + ch * 8);
            }
        }
#pragma unroll
        for (int i = 0; i < 4; ++i)
#pragma unroll
            for (int j = 0; j < 4; ++j)
                acc[i][j] = __builtin_amdgcn_mfma_f32_16x16x32_f16(af[i], bf[j], acc[i][j], 0, 0, 0);
    }

    // D layout (16x16): col = lane&15, row = (lane>>4)*4 + r   [verified m89/m91]
    const int crow0 = tm * 128 + wm + fq * 4;
    const int ccol0 = tn * 128 + wn + fr;
    if (OUT_F16) {
        _Float16* C = (_Float16*)Cv + (long long)bz * bsC;
#pragma unroll
        for (int i = 0; i < 4; ++i)
#pragma unroll
            for (int j = 0; j < 4; ++j) {
                const int col = ccol0 + j * 16;
                const float bv = bias[col];
#pragma unroll
                for (int r = 0; r < 4; ++r)
                    C[(long long)(crow0 + i*16 + r) * ldc + col] = (_Float16)(acc[i][j][r] + bv);
            }
    } else {
        float* C = (float*)Cv + (long long)bz * bsC;
#pragma unroll
        for (int i = 0; i < 4; ++i)
#pragma unroll
            for (int j = 0; j < 4; ++j) {
                const int col = ccol0 + j * 16;
#pragma unroll
                for (int r = 0; r < 4; ++r)
                    C[(long long)(crow0 + i*16 + r) * ldc + col] = acc[i][j][r];
            }
    }
}

// ---------------------------------------------------------------------------
// 256x256x(BK=64) f16->f32 GEMM, 8-phase schedule (HK-style, plain HIP).
// C[M][N] = A[M][K] * B^T, both operands [rows][K] f16 k-contiguous.
// 8 waves (2M x 4N), 128x64 output per wave. LDS 128 KiB double-buffered.
// Staging for tile t+1 issued in sub-phases 0/1 of tile t (>=3 phases of
// latency cover); raw s_barrier between sub-phases (loads stay in flight);
// one __syncthreads() gate per K-tile (vmcnt(0) drain is exact: with 2
// buffers the pipeline depth is 1 tile, and the drained loads are 3 phases
// stale). Source-side XOR chunk swizzle == read-side swizzle (involution).
// Hardcoded for grid (8, 8, Bn): M = N = 2048.
// ---------------------------------------------------------------------------
__global__ __launch_bounds__(512, 2)
void gemm256_k(const _Float16* __restrict__ Am, long long bsA, int lda,
               const _Float16* __restrict__ Bm, long long bsB, int ldb,
               float* __restrict__ Cm, long long bsC, int ldc, int K)
{
    __shared__ __align__(16) _Float16 lds[65536];   // 2 bufs x (A 16384 + B 16384)

    // bijective XCD-aware swizzle: nwg = 512, 512 % 8 == 0 -> simple form OK
    const int lin0 = (blockIdx.z * 8 + blockIdx.y) * 8 + blockIdx.x;
    const int lin  = (lin0 & 7) * 64 + (lin0 >> 3);
    const int tn   = lin & 7;
    const int tm   = (lin >> 3) & 7;
    const int bz   = lin >> 6;

    const int tid  = threadIdx.x;
    const int lane = tid & 63;
    const int wave = tid >> 6;          // 0..7
    const int wm   = (wave >> 2) * 128; // 0 / 128
    const int wn   = (wave & 3) * 64;   // 0,64,128,192
    const int fr   = lane & 15;
    const int fq   = lane >> 4;

    const _Float16* Ab = Am + (long long)bz * bsA + (long long)tm * 256 * lda;
    const _Float16* Bb = Bm + (long long)bz * bsB + (long long)tn * 256 * ldb;

    // --- staging geometry (per thread): one global_load_lds writes LDS
    // linearly (wave base + lane*16); the 16B chunk at LDS (row, c) holds
    // global chunk c ^ (row & 7)  -> swizzle applied on the SOURCE address.
    const int sr = lane >> 3;           // sub-row within an 8-row stripe
    const int ch = (lane & 7) ^ sr;     // swizzled source chunk (row&7 == sr)
    const _Float16* srcA[2][2];
    const _Float16* srcB[2][2];
#pragma unroll
    for (int h = 0; h < 2; ++h)
#pragma unroll
        for (int l = 0; l < 2; ++l) {
            const int r = h * 128 + (wave * 2 + l) * 8 + sr;   // tile row 0..255
            srcA[h][l] = Ab + (long long)r * lda + ch * 8;
            srcB[h][l] = Bb + (long long)r * ldb + ch * 8;
        }

    // LDS element destinations: buf*32768 + (B?16384:0) + h*8192
    //                           + (wave*2+l)*512 + lane*8
    auto stageA = [&](int kt, int buf) {
#pragma unroll
        for (int h = 0; h < 2; ++h)
#pragma unroll
            for (int l = 0; l < 2; ++l)
                llds16(srcA[h][l] + kt * 64,
                       lds + buf * 32768 + h * 8192 + (wave * 2 + l) * 512 + lane * 8);
    };
    auto stageB = [&](int kt, int buf) {
#pragma unroll
        for (int h = 0; h < 2; ++h)
#pragma unroll
            for (int l = 0; l < 2; ++l)
                llds16(srcB[h][l] + kt * 64,
                       lds + buf * 32768 + 16384 + h * 8192 + (wave * 2 + l) * 512 + lane * 8);
    };

    // fragment reads (swizzled): global chunk g -> LDS chunk g ^ (row&7)
    auto rdA = [&](int buf, int im, int kk) -> half8 {
        const int row = wm + im * 16 + fr;
        const int c   = (kk * 4 + fq) ^ (row & 7);
        return *(const half8*)(lds + buf * 32768 + row * 64 + c * 8);
    };
    auto rdB = [&](int buf, int jn, int kk) -> half8 {
        const int row = wn + jn * 16 + fr;
        const int c   = (kk * 4 + fq) ^ (row & 7);
        return *(const half8*)(lds + buf * 32768 + 16384 + row * 64 + c * 8);
    };

    floatx4 acc[8][4];
#pragma unroll
    for (int i = 0; i < 8; ++i)
#pragma unroll
        for (int j = 0; j < 4; ++j) acc[i][j] = (floatx4)0.0f;

    const int KT = K >> 6;              // K-tiles of 64

    stageA(0, 0);
    stageB(0, 0);
    __syncthreads();                    // gate: tile 0 visible

    for (int kt = 0; kt < KT; ++kt) {
        const int buf = kt & 1;
        half8 af[4][2], bf[2][2];
#pragma unroll
        for (int q = 0; q < 4; ++q) {
            const int nh = q >> 1;                    // 0,0,1,1
            const int mh = (q == 1 || q == 2) ? 1 : 0; // snake: 0,1,1,0
            if (q == 0 || q == 2) {
#pragma unroll
                for (int j = 0; j < 2; ++j)
#pragma unroll
                    for (int kk = 0; kk < 2; ++kk)
                        bf[j][kk] = rdB(buf, nh * 2 + j, kk);
            }
            if (q != 2) {                             // q2 reuses q1's A half
#pragma unroll
                for (int i = 0; i < 4; ++i)
#pragma unroll
                    for (int kk = 0; kk < 2; ++kk)
                        af[i][kk] = rdA(buf, mh * 4 + i, kk);
            }
            if (kt + 1 < KT) {                        // prefetch next K-tile early
                if (q == 0)      stageA(kt + 1, buf ^ 1);
                else if (q == 1) stageB(kt + 1, buf ^ 1);
            }
            __builtin_amdgcn_s_barrier();             // align waves: mem vs MFMA roles
            __builtin_amdgcn_s_setprio(1);
#pragma unroll
            for (int i = 0; i < 4; ++i)
#pragma unroll
                for (int j = 0; j < 2; ++j)
#pragma unroll
                    for (int kk = 0; kk < 2; ++kk)
                        acc[mh * 4 + i][nh * 2 + j] =
                            __builtin_amdgcn_mfma_f32_16x16x32_f16(
                                af[i][kk], bf[j][kk], acc[mh * 4 + i][nh * 2 + j], 0, 0, 0);
            __builtin_amdgcn_s_setprio(0);
            if (q < 3) __builtin_amdgcn_s_barrier();
        }
        __syncthreads();   // gate: drains (3-phase-stale) prefetch, flips buffers
    }

    // D layout (16x16): col = lane&15, row = (lane>>4)*4 + r
    float* Cb = Cm + (long long)bz * bsC;
    const int crow0 = tm * 256 + wm + fq * 4;
    const int ccol0 = tn * 256 + wn + fr;
#pragma unroll
    for (int i = 0; i < 8; ++i)
#pragma unroll
        for (int j = 0; j < 4; ++j) {
            const long long base = (long long)(crow0 + i * 16) * ldc + ccol0 + j * 16;
#pragma unroll
            for (int r = 0; r < 4; ++r)
                Cb[base + (long long)r * ldc] = acc[i][j][r];
        }
}

// ---------------------------------------------------------------------------
// Length load robust to int32-vs-int64 storage.
// ---------------------------------------------------------------------------
__device__ __forceinline__ int load_len(const int* __restrict__ p, int b)
{
    return (p[1] == 0) ? p[2 * b] : p[b];
}

// ---------------------------------------------------------------------------
// In-place masked softmax over rows of w [Bn][Sq][Sq] (f32), optional f16
// copy for the downstream o-GEMM. Mask: (r>=lenR[b]) XOR (c>=lenC[b]).
// ---------------------------------------------------------------------------
__global__ __launch_bounds__(256)
void softmax_mask_k(float* __restrict__ w, _Float16* __restrict__ wh,
                    const int* __restrict__ lenR, const int* __restrict__ lenC)
{
    const int b = blockIdx.y;
    const int r = blockIdx.x;
    const long long rowOff = ((long long)b * Sq + r) * (long long)Sq;
    float* row = w + rowOff;
    const int lr = load_len(lenR, b);
    const int lc = load_len(lenC, b);
    const bool rover = (r >= lr);
    const int tid  = threadIdx.x;
    const int lane = tid & 63;
    const int wave = tid >> 6;

    floatx4 x0 = *(const floatx4*)(row + tid * 8);
    floatx4 x1 = *(const floatx4*)(row + tid * 8 + 4);
    float v[8];
#pragma unroll
    for (int j = 0; j < 4; ++j) { v[j] = x0[j]; v[4 + j] = x1[j]; }

    float m = -3.0e38f;
#pragma unroll
    for (int j = 0; j < 8; ++j) {
        const int c = tid * 8 + j;
        if (rover != (c >= lc)) v[j] = -__builtin_inff();
        m = fmaxf(m, v[j]);
    }
#pragma unroll
    for (int off = 32; off > 0; off >>= 1) m = fmaxf(m, __shfl_xor(m, off, 64));
    __shared__ float redm[4], reds[4];
    if (lane == 0) redm[wave] = m;
    __syncthreads();
    m = fmaxf(fmaxf(redm[0], redm[1]), fmaxf(redm[2], redm[3]));

    float s = 0.f;
#pragma unroll
    for (int j = 0; j < 8; ++j) { v[j] = __expf(v[j] - m); s += v[j]; }
#pragma unroll
    for (int off = 32; off > 0; off >>= 1) s += __shfl_xor(s, off, 64);
    if (lane == 0) reds[wave] = s;
    __syncthreads();
    s = reds[0] + reds[1] + reds[2] + reds[3];
    const float inv = 1.0f / s;   // row never fully masked (lengths in [S/2,S))
#pragma unroll
    for (int j = 0; j < 4; ++j) { x0[j] = v[j] * inv; x1[j] = v[4 + j] * inv; }
    *(floatx4*)(row + tid * 8)     = x0;
    *(floatx4*)(row + tid * 8 + 4) = x1;
    if (wh != nullptr) {
        half8 h;
#pragma unroll
        for (int j = 0; j < 4; ++j) { h[j] = (_Float16)x0[j]; h[4 + j] = (_Float16)x1[j]; }
        *(half8*)(wh + rowOff + tid * 8) = h;
    }
}

// ---------------------------------------------------------------------------
extern "C" void kernel_launch(void* const* d_in, const int* in_sizes, int n_in,
                              void* d_out, int out_size, void* d_ws, size_t ws_size,
                              hipStream_t stream)
{
    (void)in_sizes; (void)n_in; (void)out_size;
    const float* k1    = (const float*)d_in[0];
    const float* k2    = (const float*)d_in[1];
    const float* pk1in = (const float*)d_in[2];
    const float* pk2in = (const float*)d_in[3];
    const float* v1    = (const float*)d_in[4];
    const float* v2    = (const float*)d_in[5];
    const float* W_k1  = (const float*)d_in[6];
    const float* b_k1  = (const float*)d_in[7];
    const float* W_k2  = (const float*)d_in[8];
    const float* b_k2  = (const float*)d_in[9];
    const float* W_pk1 = (const float*)d_in[10];
    const float* b_pk1 = (const float*)d_in[11];
    const float* W_pk2 = (const float*)d_in[12];
    const float* b_pk2 = (const float*)d_in[13];
    const int* len1 = (const int*)d_in[14];
    const int* len2 = (const int*)d_in[15];

    float* out = (float*)d_out;
    float* o1 = out;                                  // [Bn,Sq,DV]
    float* o2 = o1 + (long long)Bn * Sq * DV;         // [Bn,Sq,DV]
    float* w1 = o2 + (long long)Bn * Sq * DV;         // [Bn,Sq,Sq]
    float* w2 = w1 + (long long)Bn * Sq * Sq;         // [Bn,Sq,Sq]

    // fp16 projections live in the (dead until phase 4) o1/o2 regions.
    _Float16* k1p = (_Float16*)o1;                    // [Bn*Sq][AD]
    _Float16* k2p = k1p + (long long)Bn * Sq * AD;
    _Float16* pk1 = (_Float16*)o2;
    _Float16* pk2 = pk1 + (long long)Bn * Sq * AD;

    _Float16* vT1   = (_Float16*)d_ws;                // [Bn][DV][Sq]
    _Float16* vT2   = vT1 + (long long)Bn * DV * Sq;
    _Float16* WTk1  = vT2 + (long long)Bn * DV * Sq;  // [AD][KD]
    _Float16* WTk2  = WTk1 + AD * KD;
    _Float16* WTpk1 = WTk2 + AD * KD;                 // [AD][KD+PKD]
    _Float16* WTpk2 = WTpk1 + AD * (KD + PKD);

    const unsigned long long fixedHalves =
        2ull * Bn * DV * Sq + 2ull * AD * KD + 2ull * AD * (KD + PKD);
    _Float16* w1h = (_Float16*)d_ws + fixedHalves;    // [Bn][Sq][Sq] f16
    _Float16* w2h = w1h + (long long)Bn * Sq * Sq;
    const bool fast =
        ws_size >= (fixedHalves + 2ull * Bn * Sq * Sq) * sizeof(_Float16);

    // ---- phase 0: transpose-casts ----
    transpose_cast_k<<<dim3(AD/32, KD/32, 1), 256, 0, stream>>>(W_k1, WTk1, KD, AD, 0, 0);
    transpose_cast_k<<<dim3(AD/32, KD/32, 1), 256, 0, stream>>>(W_k2, WTk2, KD, AD, 0, 0);
    transpose_cast_k<<<dim3(AD/32, (KD+PKD)/32, 1), 256, 0, stream>>>(W_pk1, WTpk1, KD+PKD, AD, 0, 0);
    transpose_cast_k<<<dim3(AD/32, (KD+PKD)/32, 1), 256, 0, stream>>>(W_pk2, WTpk2, KD+PKD, AD, 0, 0);
    transpose_cast_k<<<dim3(DV/32, Sq/32, Bn), 256, 0, stream>>>(v1, vT1, Sq, DV,
        (long long)Sq*DV, (long long)Sq*DV);
    transpose_cast_k<<<dim3(DV/32, Sq/32, Bn), 256, 0, stream>>>(v2, vT2, Sq, DV,
        (long long)Sq*DV, (long long)Sq*DV);

    // ---- phase 1: projections (f32 A DMA'd + converted, f16 out + bias) ----
    const dim3 gProj(AD/128, (Bn*Sq)/128, 1);
    gemm_k<true, true><<<gProj, 256, 0, stream>>>(
        k1, k1, KD, KD, KD, 0,  WTk1, KD, 0,  k1p, AD, 0, b_k1, KD);
    gemm_k<true, true><<<gProj, 256, 0, stream>>>(
        k2, k2, KD, KD, KD, 0,  WTk2, KD, 0,  k2p, AD, 0, b_k2, KD);
    gemm_k<true, true><<<gProj, 256, 0, stream>>>(
        k1, pk1in, KD, KD, PKD, 0,  WTpk1, KD+PKD, 0,  pk1, AD, 0, b_pk1, KD+PKD);
    gemm_k<true, true><<<gProj, 256, 0, stream>>>(
        k2, pk2in, KD, KD, PKD, 0,  WTpk2, KD+PKD, 0,  pk2, AD, 0, b_pk2, KD+PKD);

    // ---- phase 2: scores via 256^2 8-phase GEMM, pre-transposed into w1/w2 ----
    const dim3 gScore(Sq/256, Sq/256, Bn);   // (8,8,8) = 512 blocks, 1/CU
    gemm256_k<<<gScore, 512, 0, stream>>>(
        pk2, (long long)Sq*AD, AD,
        k1p, (long long)Sq*AD, AD,
        w1, (long long)Sq*Sq, Sq, AD);
    gemm256_k<<<gScore, 512, 0, stream>>>(
        pk1, (long long)Sq*AD, AD,
        k2p, (long long)Sq*AD, AD,
        w2, (long long)Sq*Sq, Sq, AD);

    // ---- phase 3: masked softmax in place (+f16 copy when ws allows) ----
    softmax_mask_k<<<dim3(Sq, Bn), 256, 0, stream>>>(w1, fast ? w1h : nullptr, len2, len1);
    softmax_mask_k<<<dim3(Sq, Bn), 256, 0, stream>>>(w2, fast ? w2h : nullptr, len1, len2);

    // ---- phase 4: o = w @ v ----
    const dim3 gOut(DV/128, Sq/128, Bn);
    if (fast) {
        gemm_k<false, false><<<gOut, 256, 0, stream>>>(
            w1h, w1h, 0, Sq, Sq, (long long)Sq*Sq,
            vT1, Sq, (long long)DV*Sq,
            o1, DV, (long long)Sq*DV, nullptr, Sq);
        gemm_k<false, false><<<gOut, 256, 0, stream>>>(
            w2h, w2h, 0, Sq, Sq, (long long)Sq*Sq,
            vT2, Sq, (long long)DV*Sq,
            o2, DV, (long long)Sq*DV, nullptr, Sq);
    } else {
        gemm_k<true, false><<<gOut, 256, 0, stream>>>(
            w1, w1, Sq, Sq, Sq, (long long)Sq*Sq,
            vT1, Sq, (long long)DV*Sq,
            o1, DV, (long long)Sq*DV, nullptr, Sq);
        gemm_k<true, false><<<gOut, 256, 0, stream>>>(
            w2, w2, Sq, Sq, Sq, (long long)Sq*Sq,
            vT2, Sq, (long long)DV*Sq,
            o2, DV, (long long)Sq*DV, nullptr, Sq);
    }
}

// Round 2
// 854.053 us; speedup vs baseline: 1.0920x; 1.0610x over previous
//
#include <hip/hip_runtime.h>

typedef _Float16 half8 __attribute__((ext_vector_type(8)));
typedef float    floatx4 __attribute__((ext_vector_type(4)));
typedef unsigned short u16;

constexpr int Bn  = 8;
constexpr int Sq  = 2048;   // S1 == S2
constexpr int KD  = 512;    // K1_DIM == K2_DIM
constexpr int PKD = 256;
constexpr int AD  = 512;    // ATT_DIM
constexpr int DV  = 512;

// 16-byte async global->LDS DMA. LDS dest must be wave-uniform base + lane*16.
__device__ __forceinline__ void llds16(const void* g, void* l)
{
    __builtin_amdgcn_global_load_lds(
        (const __attribute__((address_space(1))) unsigned int*)g,
        (__attribute__((address_space(3))) unsigned int*)l, 16, 0, 0);
}

// ---------------------------------------------------------------------------
// transpose + cast f32 -> f16:  out[j][i] = (f16) in[i][j]
// ---------------------------------------------------------------------------
__global__ __launch_bounds__(256)
void transpose_cast_k(const float* __restrict__ in, _Float16* __restrict__ out,
                      int inRows, int inCols, long long bsIn, long long bsOut)
{
    __shared__ float t[32][33];
    const int b = blockIdx.z;
    in  += (long long)b * bsIn;
    out += (long long)b * bsOut;
    const int tx = threadIdx.x & 31;
    const int ty = threadIdx.x >> 5;     // 0..7
    const int c0 = blockIdx.x * 32;
    const int r0 = blockIdx.y * 32;
#pragma unroll
    for (int i = 0; i < 4; ++i)
        t[ty + 8*i][tx] = in[(long long)(r0 + ty + 8*i) * inCols + c0 + tx];
    __syncthreads();
#pragma unroll
    for (int i = 0; i < 4; ++i)
        out[(long long)(c0 + ty + 8*i) * inRows + r0 + tx] = (_Float16)t[tx][ty + 8*i];
}

// ---------------------------------------------------------------------------
// cast+concat f32 -> f16: out[r][0..511] = x[r][:], out[r][512..767] = y[r][:]
// rows R = Bn*Sq. 8 elems/thread, fully coalesced (16B writes, 32B reads).
// ---------------------------------------------------------------------------
__global__ __launch_bounds__(256)
void cast_cat_k(const float* __restrict__ x, const float* __restrict__ y,
                _Float16* __restrict__ out)
{
    const int idx = blockIdx.x * 256 + threadIdx.x;
    const int e   = idx * 8;                 // < 16384*768 = 12.6M, fits int
    const int r   = e / 768;
    const int c   = e % 768;
    const float* src = (c < 512) ? (x + (long long)r * 512 + c)
                                 : (y + (long long)r * 256 + (c - 512));
    const floatx4 f0 = *(const floatx4*)(src);
    const floatx4 f1 = *(const floatx4*)(src + 4);
    half8 h;
#pragma unroll
    for (int j = 0; j < 4; ++j) { h[j] = (_Float16)f0[j]; h[4 + j] = (_Float16)f1[j]; }
    *(half8*)(out + (long long)e) = h;
}

// ---------------------------------------------------------------------------
// 128x128x32 fp16 MFMA GEMM, m97-style global_load_lds staging.
// Retained only for the !fast fallback (phase 4 reading f32 w).
// ---------------------------------------------------------------------------
template<bool A_F32, bool OUT_F16>
__global__ __launch_bounds__(256, 2)
void gemm_k(const void* __restrict__ A1v, const void* __restrict__ A2v, int Ksplit,
            int lda1, int lda2, long long bsA,
            const _Float16* __restrict__ Bm, int ldb, long long bsB,
            void* __restrict__ Cv, int ldc, long long bsC,
            const float* __restrict__ bias, int K)
{
    __shared__ __align__(16) unsigned char AsRaw[A_F32 ? 16384 : 8192]; // 128x32
    __shared__ __align__(16) unsigned char BsRaw[8192];                 // 128x32 f16

    const int tid  = threadIdx.x;
    const int lane = tid & 63;
    const int wave = tid >> 6;
    const int wm   = (wave >> 1) * 64;
    const int wn   = (wave & 1) * 64;
    const int fr   = lane & 15;       // frag row (A) / col (B,D)
    const int fq   = lane >> 4;       // quad: k-offset fq*8, D-row fq*4

    const int tm = blockIdx.y, tn = blockIdx.x, bz = blockIdx.z;
    const long long aRowBase = (long long)tm * 128;
    const long long bRowBase = (long long)tn * 128;
    const _Float16* Bbase = Bm + (long long)bz * bsB;

    floatx4 acc[4][4];
#pragma unroll
    for (int i = 0; i < 4; ++i)
#pragma unroll
        for (int j = 0; j < 4; ++j) acc[i][j] = (floatx4)0.0f;

    for (int k0 = 0; k0 < K; k0 += 32) {
        __syncthreads();   // previous tile's ds_reads complete before overwrite

        if (A_F32) {
            const float* A1 = (const float*)A1v + (long long)bz * bsA;
            const float* A2 = (const float*)A2v;
#pragma unroll
            for (int is = 0; is < 4; ++is) {
                const int r  = (tid >> 3) + is * 32;       // 0..127
                const int ch = (tid & 7) ^ (r & 7);        // swizzled 16B chunk
                const int kk = k0 + ch * 4;                // f32 col
                const float* src = (kk < Ksplit)
                    ? A1 + (aRowBase + r) * lda1 + kk
                    : A2 + (aRowBase + r) * lda2 + (kk - Ksplit);
                llds16(src, AsRaw + tid * 16 + is * 4096);
            }
        } else {
            const _Float16* A1 = (const _Float16*)A1v + (long long)bz * bsA;
#pragma unroll
            for (int is = 0; is < 2; ++is) {
                const int r  = (tid >> 2) + is * 64;       // 0..127
                const int ch = (tid & 3) ^ (r & 3);
                llds16(A1 + (aRowBase + r) * lda1 + k0 + ch * 8,
                       AsRaw + tid * 16 + is * 4096);
            }
        }
#pragma unroll
        for (int is = 0; is < 2; ++is) {
            const int r  = (tid >> 2) + is * 64;
            const int ch = (tid & 3) ^ (r & 3);
            llds16(Bbase + (bRowBase + r) * ldb + k0 + ch * 8,
                   BsRaw + tid * 16 + is * 4096);
        }

        __syncthreads();   // drains vmcnt(0): DMA visible to all waves

        half8 af[4], bf[4];
        if (A_F32) {
            const float* As32 = (const float*)AsRaw;
#pragma unroll
            for (int i = 0; i < 4; ++i) {
                const int r  = wm + i * 16 + fr;
                const int c0 = ((2 * fq) ^ (r & 7)) * 4;
                const int c1 = ((2 * fq + 1) ^ (r & 7)) * 4;
                floatx4 f0 = *(const floatx4*)(As32 + r * 32 + c0);
                floatx4 f1 = *(const floatx4*)(As32 + r * 32 + c1);
                half8 h;
#pragma unroll
                for (int j = 0; j < 4; ++j) {
                    h[j]     = (_Float16)f0[j];
                    h[4 + j] = (_Float16)f1[j];
                }
                af[i] = h;
            }
        } else {
            const _Float16* As16 = (const _Float16*)AsRaw;
#pragma unroll
            for (int i = 0; i < 4; ++i) {
                const int r  = wm + i * 16 + fr;
                const int ch = fq ^ (r & 3);
                af[i] = *(const half8*)(As16 + r * 32 + ch * 8);
            }
        }
        {
            const _Float16* Bs16 = (const _Float16*)BsRaw;
#pragma unroll
            for (int j = 0; j < 4; ++j) {
                const int r  = wn + j * 16 + fr;
                const int ch = fq ^ (r & 3);
                bf[j] = *(const half8*)(Bs16 + r * 32 + ch * 8);
            }
        }
#pragma unroll
        for (int i = 0; i < 4; ++i)
#pragma unroll
            for (int j = 0; j < 4; ++j)
                acc[i][j] = __builtin_amdgcn_mfma_f32_16x16x32_f16(af[i], bf[j], acc[i][j], 0, 0, 0);
    }

    // D layout (16x16): col = lane&15, row = (lane>>4)*4 + r   [verified m89/m91]
    const int crow0 = tm * 128 + wm + fq * 4;
    const int ccol0 = tn * 128 + wn + fr;
    if (OUT_F16) {
        _Float16* C = (_Float16*)Cv + (long long)bz * bsC;
#pragma unroll
        for (int i = 0; i < 4; ++i)
#pragma unroll
            for (int j = 0; j < 4; ++j) {
                const int col = ccol0 + j * 16;
                const float bv = bias[col];
#pragma unroll
                for (int r = 0; r < 4; ++r)
                    C[(long long)(crow0 + i*16 + r) * ldc + col] = (_Float16)(acc[i][j][r] + bv);
            }
    } else {
        float* C = (float*)Cv + (long long)bz * bsC;
#pragma unroll
        for (int i = 0; i < 4; ++i)
#pragma unroll
            for (int j = 0; j < 4; ++j) {
                const int col = ccol0 + j * 16;
#pragma unroll
                for (int r = 0; r < 4; ++r)
                    C[(long long)(crow0 + i*16 + r) * ldc + col] = acc[i][j][r];
            }
    }
}

// ---------------------------------------------------------------------------
// 256x256x(BK=64) f16->f32 GEMM, 8-phase schedule (HK-style, plain HIP).
// C[M][N] = A[M][K] * B^T, both operands [rows][K] f16 k-contiguous.
// Hardcoded for grid (8, 8, Bn): M = N = 2048. (phase 2 — unchanged, proven)
// ---------------------------------------------------------------------------
__global__ __launch_bounds__(512, 2)
void gemm256_k(const _Float16* __restrict__ Am, long long bsA, int lda,
               const _Float16* __restrict__ Bm, long long bsB, int ldb,
               float* __restrict__ Cm, long long bsC, int ldc, int K)
{
    __shared__ __align__(16) _Float16 lds[65536];   // 2 bufs x (A 16384 + B 16384)

    // bijective XCD-aware swizzle: nwg = 512, 512 % 8 == 0 -> simple form OK
    const int lin0 = (blockIdx.z * 8 + blockIdx.y) * 8 + blockIdx.x;
    const int lin  = (lin0 & 7) * 64 + (lin0 >> 3);
    const int tn   = lin & 7;
    const int tm   = (lin >> 3) & 7;
    const int bz   = lin >> 6;

    const int tid  = threadIdx.x;
    const int lane = tid & 63;
    const int wave = tid >> 6;          // 0..7
    const int wm   = (wave >> 2) * 128; // 0 / 128
    const int wn   = (wave & 3) * 64;   // 0,64,128,192
    const int fr   = lane & 15;
    const int fq   = lane >> 4;

    const _Float16* Ab = Am + (long long)bz * bsA + (long long)tm * 256 * lda;
    const _Float16* Bb = Bm + (long long)bz * bsB + (long long)tn * 256 * ldb;

    const int sr = lane >> 3;           // sub-row within an 8-row stripe
    const int ch = (lane & 7) ^ sr;     // swizzled source chunk (row&7 == sr)
    const _Float16* srcA[2][2];
    const _Float16* srcB[2][2];
#pragma unroll
    for (int h = 0; h < 2; ++h)
#pragma unroll
        for (int l = 0; l < 2; ++l) {
            const int r = h * 128 + (wave * 2 + l) * 8 + sr;   // tile row 0..255
            srcA[h][l] = Ab + (long long)r * lda + ch * 8;
            srcB[h][l] = Bb + (long long)r * ldb + ch * 8;
        }

    auto stageA = [&](int kt, int buf) {
#pragma unroll
        for (int h = 0; h < 2; ++h)
#pragma unroll
            for (int l = 0; l < 2; ++l)
                llds16(srcA[h][l] + kt * 64,
                       lds + buf * 32768 + h * 8192 + (wave * 2 + l) * 512 + lane * 8);
    };
    auto stageB = [&](int kt, int buf) {
#pragma unroll
        for (int h = 0; h < 2; ++h)
#pragma unroll
            for (int l = 0; l < 2; ++l)
                llds16(srcB[h][l] + kt * 64,
                       lds + buf * 32768 + 16384 + h * 8192 + (wave * 2 + l) * 512 + lane * 8);
    };

    auto rdA = [&](int buf, int im, int kk) -> half8 {
        const int row = wm + im * 16 + fr;
        const int c   = (kk * 4 + fq) ^ (row & 7);
        return *(const half8*)(lds + buf * 32768 + row * 64 + c * 8);
    };
    auto rdB = [&](int buf, int jn, int kk) -> half8 {
        const int row = wn + jn * 16 + fr;
        const int c   = (kk * 4 + fq) ^ (row & 7);
        return *(const half8*)(lds + buf * 32768 + 16384 + row * 64 + c * 8);
    };

    floatx4 acc[8][4];
#pragma unroll
    for (int i = 0; i < 8; ++i)
#pragma unroll
        for (int j = 0; j < 4; ++j) acc[i][j] = (floatx4)0.0f;

    const int KT = K >> 6;              // K-tiles of 64

    stageA(0, 0);
    stageB(0, 0);
    __syncthreads();                    // gate: tile 0 visible

    for (int kt = 0; kt < KT; ++kt) {
        const int buf = kt & 1;
        half8 af[4][2], bf[2][2];
#pragma unroll
        for (int q = 0; q < 4; ++q) {
            const int nh = q >> 1;                    // 0,0,1,1
            const int mh = (q == 1 || q == 2) ? 1 : 0; // snake: 0,1,1,0
            if (q == 0 || q == 2) {
#pragma unroll
                for (int j = 0; j < 2; ++j)
#pragma unroll
                    for (int kk = 0; kk < 2; ++kk)
                        bf[j][kk] = rdB(buf, nh * 2 + j, kk);
            }
            if (q != 2) {                             // q2 reuses q1's A half
#pragma unroll
                for (int i = 0; i < 4; ++i)
#pragma unroll
                    for (int kk = 0; kk < 2; ++kk)
                        af[i][kk] = rdA(buf, mh * 4 + i, kk);
            }
            if (kt + 1 < KT) {                        // prefetch next K-tile early
                if (q == 0)      stageA(kt + 1, buf ^ 1);
                else if (q == 1) stageB(kt + 1, buf ^ 1);
            }
            __builtin_amdgcn_s_barrier();             // align waves: mem vs MFMA roles
            __builtin_amdgcn_s_setprio(1);
#pragma unroll
            for (int i = 0; i < 4; ++i)
#pragma unroll
                for (int j = 0; j < 2; ++j)
#pragma unroll
                    for (int kk = 0; kk < 2; ++kk)
                        acc[mh * 4 + i][nh * 2 + j] =
                            __builtin_amdgcn_mfma_f32_16x16x32_f16(
                                af[i][kk], bf[j][kk], acc[mh * 4 + i][nh * 2 + j], 0, 0, 0);
            __builtin_amdgcn_s_setprio(0);
            if (q < 3) __builtin_amdgcn_s_barrier();
        }
        __syncthreads();   // gate: drains (3-phase-stale) prefetch, flips buffers
    }

    // D layout (16x16): col = lane&15, row = (lane>>4)*4 + r
    float* Cb = Cm + (long long)bz * bsC;
    const int crow0 = tm * 256 + wm + fq * 4;
    const int ccol0 = tn * 256 + wn + fr;
#pragma unroll
    for (int i = 0; i < 8; ++i)
#pragma unroll
        for (int j = 0; j < 4; ++j) {
            const long long base = (long long)(crow0 + i * 16) * ldc + ccol0 + j * 16;
#pragma unroll
            for (int r = 0; r < 4; ++r)
                Cb[base + (long long)r * ldc] = acc[i][j][r];
        }
}

// ---------------------------------------------------------------------------
// 256x128x(BK=64) f16 GEMM, same 4-subphase counted-prefetch schedule as
// gemm256_k (parameter variant: BN=128, per-wave 128x32, acc[8][2], 96 KiB
// LDS). For N=512 problems: grid x = N/128 keeps all 256 CUs busy.
// Two pointer sets selected by blockIdx.z >= zsplit (launch folding).
// C = A[M][K] * B^T; optional f16 output with bias (projections).
// ---------------------------------------------------------------------------
template<bool OUT_F16>
__global__ __launch_bounds__(512, 2)
void gemm256x128_k(const _Float16* __restrict__ A0, const _Float16* __restrict__ A1,
                   long long bsA, int lda,
                   const _Float16* __restrict__ B0, const _Float16* __restrict__ B1,
                   long long bsB, int ldb,
                   void* __restrict__ C0, void* __restrict__ C1,
                   long long bsC, int ldc,
                   const float* __restrict__ bias0, const float* __restrict__ bias1,
                   int K, int zsplit)
{
    __shared__ __align__(16) _Float16 lds[49152];   // 2 bufs x (A 16384 + B 8192)

    // bijective XCD swizzle (all grids here have nwg % 8 == 0)
    const int gx   = gridDim.x, gy = gridDim.y;
    const int nwg  = gx * gy * gridDim.z;
    const int lin0 = (blockIdx.z * gy + blockIdx.y) * gx + blockIdx.x;
    const int cpx  = nwg >> 3;
    const int lin  = (lin0 & 7) * cpx + (lin0 >> 3);
    const int tn   = lin % gx;
    const int tmp2 = lin / gx;
    const int tm   = tmp2 % gy;
    const int bz   = tmp2 / gy;

    const bool sel = (bz >= zsplit);
    const int  bzl = sel ? (bz - zsplit) : bz;
    const _Float16* Am = sel ? A1 : A0;
    const _Float16* Bm = sel ? B1 : B0;

    const int tid  = threadIdx.x;
    const int lane = tid & 63;
    const int wave = tid >> 6;          // 0..7
    const int wm   = (wave >> 2) * 128; // 0 / 128
    const int wn   = (wave & 3) * 32;   // 0,32,64,96
    const int fr   = lane & 15;
    const int fq   = lane >> 4;

    const _Float16* Ab = Am + (long long)bzl * bsA + (long long)tm * 256 * lda;
    const _Float16* Bb = Bm + (long long)bzl * bsB + (long long)tn * 128 * ldb;

    const int sr = lane >> 3;
    const int ch = (lane & 7) ^ sr;     // source-side swizzle (involution)
    const _Float16* srcA[2][2];
    const _Float16* srcB[2];
#pragma unroll
    for (int h = 0; h < 2; ++h)
#pragma unroll
        for (int l = 0; l < 2; ++l)
            srcA[h][l] = Ab + (long long)(h * 128 + (wave * 2 + l) * 8 + sr) * lda + ch * 8;
#pragma unroll
    for (int l = 0; l < 2; ++l)
        srcB[l] = Bb + (long long)((wave * 2 + l) * 8 + sr) * ldb + ch * 8;

    auto stageA = [&](int kt, int buf) {
#pragma unroll
        for (int h = 0; h < 2; ++h)
#pragma unroll
            for (int l = 0; l < 2; ++l)
                llds16(srcA[h][l] + kt * 64,
                       lds + buf * 24576 + h * 8192 + (wave * 2 + l) * 512 + lane * 8);
    };
    auto stageB = [&](int kt, int buf) {
#pragma unroll
        for (int l = 0; l < 2; ++l)
            llds16(srcB[l] + kt * 64,
                   lds + buf * 24576 + 16384 + (wave * 2 + l) * 512 + lane * 8);
    };

    auto rdA = [&](int buf, int im, int kk) -> half8 {
        const int row = wm + im * 16 + fr;
        const int c   = (kk * 4 + fq) ^ (row & 7);
        return *(const half8*)(lds + buf * 24576 + row * 64 + c * 8);
    };
    auto rdB = [&](int buf, int jn, int kk) -> half8 {
        const int row = wn + jn * 16 + fr;
        const int c   = (kk * 4 + fq) ^ (row & 7);
        return *(const half8*)(lds + buf * 24576 + 16384 + row * 64 + c * 8);
    };

    floatx4 acc[8][2];
#pragma unroll
    for (int i = 0; i < 8; ++i)
#pragma unroll
        for (int j = 0; j < 2; ++j) acc[i][j] = (floatx4)0.0f;

    const int KT = K >> 6;

    stageA(0, 0);
    stageB(0, 0);
    __syncthreads();

    for (int kt = 0; kt < KT; ++kt) {
        const int buf = kt & 1;
        half8 afA[4][2], afB[4][2], bf0[2], bf1[2];

        // q0: n0 frags + A low half; prefetch next A; MFMA m0 x n0
#pragma unroll
        for (int kk = 0; kk < 2; ++kk) bf0[kk] = rdB(buf, 0, kk);
#pragma unroll
        for (int i = 0; i < 4; ++i)
#pragma unroll
            for (int kk = 0; kk < 2; ++kk) afA[i][kk] = rdA(buf, i, kk);
        if (kt + 1 < KT) stageA(kt + 1, buf ^ 1);
        __builtin_amdgcn_s_barrier();
        __builtin_amdgcn_s_setprio(1);
#pragma unroll
        for (int i = 0; i < 4; ++i)
#pragma unroll
            for (int kk = 0; kk < 2; ++kk)
                acc[i][0] = __builtin_amdgcn_mfma_f32_16x16x32_f16(afA[i][kk], bf0[kk], acc[i][0], 0, 0, 0);
        __builtin_amdgcn_s_setprio(0);
        __builtin_amdgcn_s_barrier();

        // q1: A high half; prefetch next B; MFMA m1 x n0
#pragma unroll
        for (int i = 0; i < 4; ++i)
#pragma unroll
            for (int kk = 0; kk < 2; ++kk) afB[i][kk] = rdA(buf, 4 + i, kk);
        if (kt + 1 < KT) stageB(kt + 1, buf ^ 1);
        __builtin_amdgcn_s_barrier();
        __builtin_amdgcn_s_setprio(1);
#pragma unroll
        for (int i = 0; i < 4; ++i)
#pragma unroll
            for (int kk = 0; kk < 2; ++kk)
                acc[4 + i][0] = __builtin_amdgcn_mfma_f32_16x16x32_f16(afB[i][kk], bf0[kk], acc[4 + i][0], 0, 0, 0);
        __builtin_amdgcn_s_setprio(0);
        __builtin_amdgcn_s_barrier();

        // q2: n1 frags; MFMA m1 x n1 (reuse afB)
#pragma unroll
        for (int kk = 0; kk < 2; ++kk) bf1[kk] = rdB(buf, 1, kk);
        __builtin_amdgcn_s_barrier();
        __builtin_amdgcn_s_setprio(1);
#pragma unroll
        for (int i = 0; i < 4; ++i)
#pragma unroll
            for (int kk = 0; kk < 2; ++kk)
                acc[4 + i][1] = __builtin_amdgcn_mfma_f32_16x16x32_f16(afB[i][kk], bf1[kk], acc[4 + i][1], 0, 0, 0);
        __builtin_amdgcn_s_setprio(0);
        __builtin_amdgcn_s_barrier();

        // q3: MFMA m0 x n1 (reuse afA, bf1); no loads
        __builtin_amdgcn_s_setprio(1);
#pragma unroll
        for (int i = 0; i < 4; ++i)
#pragma unroll
            for (int kk = 0; kk < 2; ++kk)
                acc[i][1] = __builtin_amdgcn_mfma_f32_16x16x32_f16(afA[i][kk], bf1[kk], acc[i][1], 0, 0, 0);
        __builtin_amdgcn_s_setprio(0);

        __syncthreads();   // gate: drains (stale) prefetch, flips buffers
    }

    // D layout (16x16): col = lane&15, row = (lane>>4)*4 + r
    const int crow0 = tm * 256 + wm + fq * 4;
    const int ccol0 = tn * 128 + wn + fr;
    if (OUT_F16) {
        const float* bias = sel ? bias1 : bias0;
        _Float16* C = (_Float16*)(sel ? C1 : C0) + (long long)bzl * bsC;
#pragma unroll
        for (int i = 0; i < 8; ++i)
#pragma unroll
            for (int j = 0; j < 2; ++j) {
                const int col = ccol0 + j * 16;
                const float bv = bias[col];
#pragma unroll
                for (int r = 0; r < 4; ++r)
                    C[(long long)(crow0 + i * 16 + r) * ldc + col] = (_Float16)(acc[i][j][r] + bv);
            }
    } else {
        float* C = (float*)(sel ? C1 : C0) + (long long)bzl * bsC;
#pragma unroll
        for (int i = 0; i < 8; ++i)
#pragma unroll
            for (int j = 0; j < 2; ++j) {
                const int col = ccol0 + j * 16;
#pragma unroll
                for (int r = 0; r < 4; ++r)
                    C[(long long)(crow0 + i * 16 + r) * ldc + col] = acc[i][j][r];
            }
    }
}

// ---------------------------------------------------------------------------
// Length load robust to int32-vs-int64 storage.
// ---------------------------------------------------------------------------
__device__ __forceinline__ int load_len(const int* __restrict__ p, int b)
{
    return (p[1] == 0) ? p[2 * b] : p[b];
}

// ---------------------------------------------------------------------------
// In-place masked softmax over rows of w [Bn][Sq][Sq] (f32), optional f16
// copy for the downstream o-GEMM. Mask: (r>=lenR[b]) XOR (c>=lenC[b]).
// ---------------------------------------------------------------------------
__global__ __launch_bounds__(256)
void softmax_mask_k(float* __restrict__ w, _Float16* __restrict__ wh,
                    const int* __restrict__ lenR, const int* __restrict__ lenC)
{
    const int b = blockIdx.y;
    const int r = blockIdx.x;
    const long long rowOff = ((long long)b * Sq + r) * (long long)Sq;
    float* row = w + rowOff;
    const int lr = load_len(lenR, b);
    const int lc = load_len(lenC, b);
    const bool rover = (r >= lr);
    const int tid  = threadIdx.x;
    const int lane = tid & 63;
    const int wave = tid >> 6;

    floatx4 x0 = *(const floatx4*)(row + tid * 8);
    floatx4 x1 = *(const floatx4*)(row + tid * 8 + 4);
    float v[8];
#pragma unroll
    for (int j = 0; j < 4; ++j) { v[j] = x0[j]; v[4 + j] = x1[j]; }

    float m = -3.0e38f;
#pragma unroll
    for (int j = 0; j < 8; ++j) {
        const int c = tid * 8 + j;
        if (rover != (c >= lc)) v[j] = -__builtin_inff();
        m = fmaxf(m, v[j]);
    }
#pragma unroll
    for (int off = 32; off > 0; off >>= 1) m = fmaxf(m, __shfl_xor(m, off, 64));
    __shared__ float redm[4], reds[4];
    if (lane == 0) redm[wave] = m;
    __syncthreads();
    m = fmaxf(fmaxf(redm[0], redm[1]), fmaxf(redm[2], redm[3]));

    float s = 0.f;
#pragma unroll
    for (int j = 0; j < 8; ++j) { v[j] = __expf(v[j] - m); s += v[j]; }
#pragma unroll
    for (int off = 32; off > 0; off >>= 1) s += __shfl_xor(s, off, 64);
    if (lane == 0) reds[wave] = s;
    __syncthreads();
    s = reds[0] + reds[1] + reds[2] + reds[3];
    const float inv = 1.0f / s;   // row never fully masked (lengths in [S/2,S))
#pragma unroll
    for (int j = 0; j < 4; ++j) { x0[j] = v[j] * inv; x1[j] = v[4 + j] * inv; }
    *(floatx4*)(row + tid * 8)     = x0;
    *(floatx4*)(row + tid * 8 + 4) = x1;
    if (wh != nullptr) {
        half8 h;
#pragma unroll
        for (int j = 0; j < 4; ++j) { h[j] = (_Float16)x0[j]; h[4 + j] = (_Float16)x1[j]; }
        *(half8*)(wh + rowOff + tid * 8) = h;
    }
}

// ---------------------------------------------------------------------------
extern "C" void kernel_launch(void* const* d_in, const int* in_sizes, int n_in,
                              void* d_out, int out_size, void* d_ws, size_t ws_size,
                              hipStream_t stream)
{
    (void)in_sizes; (void)n_in; (void)out_size;
    const float* k1    = (const float*)d_in[0];
    const float* k2    = (const float*)d_in[1];
    const float* pk1in = (const float*)d_in[2];
    const float* pk2in = (const float*)d_in[3];
    const float* v1    = (const float*)d_in[4];
    const float* v2    = (const float*)d_in[5];
    const float* W_k1  = (const float*)d_in[6];
    const float* b_k1  = (const float*)d_in[7];
    const float* W_k2  = (const float*)d_in[8];
    const float* b_k2  = (const float*)d_in[9];
    const float* W_pk1 = (const float*)d_in[10];
    const float* b_pk1 = (const float*)d_in[11];
    const float* W_pk2 = (const float*)d_in[12];
    const float* b_pk2 = (const float*)d_in[13];
    const int* len1 = (const int*)d_in[14];
    const int* len2 = (const int*)d_in[15];

    float* out = (float*)d_out;
    float* o1 = out;                                  // [Bn,Sq,DV]
    float* o2 = o1 + (long long)Bn * Sq * DV;         // [Bn,Sq,DV]
    float* w1 = o2 + (long long)Bn * Sq * DV;         // [Bn,Sq,Sq]
    float* w2 = w1 + (long long)Bn * Sq * Sq;         // [Bn,Sq,Sq]

    // fp16 intermediates live in the (dead until phase 4) o1/o2 regions.
    _Float16* k1p = (_Float16*)o1;                    // [Bn*Sq][AD]
    _Float16* k2p = k1p + (long long)Bn * Sq * AD;
    _Float16* pk1 = (_Float16*)o2;
    _Float16* pk2 = pk1 + (long long)Bn * Sq * AD;
    _Float16* cat1 = pk2 + (long long)Bn * Sq * AD;   // [Bn*Sq][KD+PKD] f16
    _Float16* cat2 = cat1 + (long long)Bn * Sq * (KD + PKD);
    // o2 region capacity: Bn*Sq*DV f32 = 67.1M halves; used: 2*16.8 + 2*12.6 = 58.8M  OK

    _Float16* vT1   = (_Float16*)d_ws;                // [Bn][DV][Sq]
    _Float16* vT2   = vT1 + (long long)Bn * DV * Sq;
    _Float16* WTk1  = vT2 + (long long)Bn * DV * Sq;  // [AD][KD]
    _Float16* WTk2  = WTk1 + AD * KD;
    _Float16* WTpk1 = WTk2 + AD * KD;                 // [AD][KD+PKD]
    _Float16* WTpk2 = WTpk1 + AD * (KD + PKD);

    const unsigned long long fixedHalves =
        2ull * Bn * DV * Sq + 2ull * AD * KD + 2ull * AD * (KD + PKD);
    _Float16* w1h = (_Float16*)d_ws + fixedHalves;    // [Bn][Sq][Sq] f16
    _Float16* w2h = w1h + (long long)Bn * Sq * Sq;
    const bool fast =
        ws_size >= (fixedHalves + 2ull * Bn * Sq * Sq) * sizeof(_Float16);

    // ---- phase 0: transpose-casts + concat-casts ----
    transpose_cast_k<<<dim3(AD/32, KD/32, 1), 256, 0, stream>>>(W_k1, WTk1, KD, AD, 0, 0);
    transpose_cast_k<<<dim3(AD/32, KD/32, 1), 256, 0, stream>>>(W_k2, WTk2, KD, AD, 0, 0);
    transpose_cast_k<<<dim3(AD/32, (KD+PKD)/32, 1), 256, 0, stream>>>(W_pk1, WTpk1, KD+PKD, AD, 0, 0);
    transpose_cast_k<<<dim3(AD/32, (KD+PKD)/32, 1), 256, 0, stream>>>(W_pk2, WTpk2, KD+PKD, AD, 0, 0);
    transpose_cast_k<<<dim3(DV/32, Sq/32, Bn), 256, 0, stream>>>(v1, vT1, Sq, DV,
        (long long)Sq*DV, (long long)Sq*DV);
    transpose_cast_k<<<dim3(DV/32, Sq/32, Bn), 256, 0, stream>>>(v2, vT2, Sq, DV,
        (long long)Sq*DV, (long long)Sq*DV);
    cast_cat_k<<<dim3((Bn*Sq*(KD+PKD))/(256*8), 1, 1), 256, 0, stream>>>(k1, pk1in, cat1);
    cast_cat_k<<<dim3((Bn*Sq*(KD+PKD))/(256*8), 1, 1), 256, 0, stream>>>(k2, pk2in, cat2);

    // ---- phase 1: projections, f16 256x128 8-phase GEMMs (folded pairs) ----
    // k-proj: A = cat (first KD cols via lda=768), K = KD
    gemm256x128_k<true><<<dim3(AD/128, (Bn*Sq)/256, 2), 512, 0, stream>>>(
        cat1, cat2, 0, KD+PKD,
        WTk1, WTk2, 0, KD,
        k1p, k2p, 0, AD,
        b_k1, b_k2, KD, 1);
    // pk-proj: A = cat (all cols), K = KD+PKD
    gemm256x128_k<true><<<dim3(AD/128, (Bn*Sq)/256, 2), 512, 0, stream>>>(
        cat1, cat2, 0, KD+PKD,
        WTpk1, WTpk2, 0, KD+PKD,
        pk1, pk2, 0, AD,
        b_pk1, b_pk2, KD+PKD, 1);

    // ---- phase 2: scores via 256^2 8-phase GEMM, pre-transposed into w1/w2 ----
    const dim3 gScore(Sq/256, Sq/256, Bn);   // (8,8,8) = 512 blocks, 1/CU
    gemm256_k<<<gScore, 512, 0, stream>>>(
        pk2, (long long)Sq*AD, AD,
        k1p, (long long)Sq*AD, AD,
        w1, (long long)Sq*Sq, Sq, AD);
    gemm256_k<<<gScore, 512, 0, stream>>>(
        pk1, (long long)Sq*AD, AD,
        k2p, (long long)Sq*AD, AD,
        w2, (long long)Sq*Sq, Sq, AD);

    // ---- phase 3: masked softmax in place (+f16 copy when ws allows) ----
    softmax_mask_k<<<dim3(Sq, Bn), 256, 0, stream>>>(w1, fast ? w1h : nullptr, len2, len1);
    softmax_mask_k<<<dim3(Sq, Bn), 256, 0, stream>>>(w2, fast ? w2h : nullptr, len1, len2);

    // ---- phase 4: o = w @ v (folded into one launch, z = 16) ----
    if (fast) {
        gemm256x128_k<false><<<dim3(DV/128, Sq/256, 2*Bn), 512, 0, stream>>>(
            w1h, w2h, (long long)Sq*Sq, Sq,
            vT1, vT2, (long long)DV*Sq, Sq,
            o1, o2, (long long)Sq*DV, DV,
            nullptr, nullptr, Sq, Bn);
    } else {
        const dim3 gOut(DV/128, Sq/128, Bn);
        gemm_k<true, false><<<gOut, 256, 0, stream>>>(
            w1, w1, Sq, Sq, Sq, (long long)Sq*Sq,
            vT1, Sq, (long long)DV*Sq,
            o1, DV, (long long)Sq*DV, nullptr, Sq);
        gemm_k<true, false><<<gOut, 256, 0, stream>>>(
            w2, w2, Sq, Sq, Sq, (long long)Sq*Sq,
            vT2, Sq, (long long)DV*Sq,
            o2, DV, (long long)Sq*DV, nullptr, Sq);
    }
}

// Round 3
// 792.073 us; speedup vs baseline: 1.1774x; 1.0782x over previous
//
#include <hip/hip_runtime.h>

typedef _Float16 half8 __attribute__((ext_vector_type(8)));
typedef float    floatx4 __attribute__((ext_vector_type(4)));
typedef unsigned short u16;

constexpr int Bn  = 8;
constexpr int Sq  = 2048;   // S1 == S2
constexpr int KD  = 512;    // K1_DIM == K2_DIM
constexpr int PKD = 256;
constexpr int AD  = 512;    // ATT_DIM
constexpr int DV  = 512;

// 16-byte async global->LDS DMA. LDS dest must be wave-uniform base + lane*16.
__device__ __forceinline__ void llds16(const void* g, void* l)
{
    __builtin_amdgcn_global_load_lds(
        (const __attribute__((address_space(1))) unsigned int*)g,
        (__attribute__((address_space(3))) unsigned int*)l, 16, 0, 0);
}

// ---------------------------------------------------------------------------
// transpose + cast f32 -> f16 (dual-source fold): out[j][i] = (f16) in[i][j]
// z < zsplit: batch z of (in0,out0); else batch z-zsplit of (in1,out1).
// ---------------------------------------------------------------------------
__global__ __launch_bounds__(256)
void transpose_cast_k(const float* __restrict__ in0, const float* __restrict__ in1,
                      _Float16* __restrict__ out0, _Float16* __restrict__ out1,
                      int inRows, int inCols, long long bsIn, long long bsOut,
                      int zsplit)
{
    __shared__ float t[32][33];
    const int bz = blockIdx.z;
    const bool sel = (bz >= zsplit);
    const int b = sel ? bz - zsplit : bz;
    const float* in = (sel ? in1 : in0) + (long long)b * bsIn;
    _Float16* out = (sel ? out1 : out0) + (long long)b * bsOut;
    const int tx = threadIdx.x & 31;
    const int ty = threadIdx.x >> 5;     // 0..7
    const int c0 = blockIdx.x * 32;
    const int r0 = blockIdx.y * 32;
#pragma unroll
    for (int i = 0; i < 4; ++i)
        t[ty + 8*i][tx] = in[(long long)(r0 + ty + 8*i) * inCols + c0 + tx];
    __syncthreads();
#pragma unroll
    for (int i = 0; i < 4; ++i)
        out[(long long)(c0 + ty + 8*i) * inRows + r0 + tx] = (_Float16)t[tx][ty + 8*i];
}

// ---------------------------------------------------------------------------
// All four weight transposes in one launch. WT[n][k] = (f16) W[k][n].
// z: 0=W_k1, 1=W_k2 (K'=512), 2=W_pk1, 3=W_pk2 (K'=768). grid (16, 24, 4).
// ---------------------------------------------------------------------------
__global__ __launch_bounds__(256)
void wT_all_k(const float* __restrict__ Wk1, const float* __restrict__ Wk2,
              const float* __restrict__ Wpk1, const float* __restrict__ Wpk2,
              _Float16* __restrict__ Tk1, _Float16* __restrict__ Tk2,
              _Float16* __restrict__ Tpk1, _Float16* __restrict__ Tpk2)
{
    const int z = blockIdx.z;
    const float* W; _Float16* T; int Krows;
    if      (z == 0) { W = Wk1;  T = Tk1;  Krows = KD; }
    else if (z == 1) { W = Wk2;  T = Tk2;  Krows = KD; }
    else if (z == 2) { W = Wpk1; T = Tpk1; Krows = KD + PKD; }
    else             { W = Wpk2; T = Tpk2; Krows = KD + PKD; }
    const int r0 = blockIdx.y * 32;          // k index
    if (r0 >= Krows) return;
    const int c0 = blockIdx.x * 32;          // n index (AD)
    __shared__ float t[32][33];
    const int tx = threadIdx.x & 31;
    const int ty = threadIdx.x >> 5;
#pragma unroll
    for (int i = 0; i < 4; ++i)
        t[ty + 8*i][tx] = W[(long long)(r0 + ty + 8*i) * AD + c0 + tx];
    __syncthreads();
#pragma unroll
    for (int i = 0; i < 4; ++i)
        T[(long long)(c0 + ty + 8*i) * Krows + r0 + tx] = (_Float16)t[tx][ty + 8*i];
}

// ---------------------------------------------------------------------------
// cast+concat f32 -> f16 (both sides): out[r][0..511]=x, out[r][512..767]=y.
// grid (6144, 1, 2): z selects side.
// ---------------------------------------------------------------------------
__global__ __launch_bounds__(256)
void cast_cat_k(const float* __restrict__ x0, const float* __restrict__ y0,
                _Float16* __restrict__ o0,
                const float* __restrict__ x1, const float* __restrict__ y1,
                _Float16* __restrict__ o1)
{
    const bool sel = (blockIdx.z != 0);
    const float* x = sel ? x1 : x0;
    const float* y = sel ? y1 : y0;
    _Float16* out = sel ? o1 : o0;
    const int idx = blockIdx.x * 256 + threadIdx.x;
    const int e   = idx * 8;                 // < 16384*768 = 12.6M, fits int
    const int r   = e / 768;
    const int c   = e % 768;
    const float* src = (c < 512) ? (x + (long long)r * 512 + c)
                                 : (y + (long long)r * 256 + (c - 512));
    const floatx4 f0 = *(const floatx4*)(src);
    const floatx4 f1 = *(const floatx4*)(src + 4);
    half8 h;
#pragma unroll
    for (int j = 0; j < 4; ++j) { h[j] = (_Float16)f0[j]; h[4 + j] = (_Float16)f1[j]; }
    *(half8*)(out + (long long)e) = h;
}

// ---------------------------------------------------------------------------
// 128x128x32 fp16 MFMA GEMM (m97-style). Retained only for the !fast
// fallback (phase 4 reading f32 w).
// ---------------------------------------------------------------------------
template<bool A_F32, bool OUT_F16>
__global__ __launch_bounds__(256, 2)
void gemm_k(const void* __restrict__ A1v, const void* __restrict__ A2v, int Ksplit,
            int lda1, int lda2, long long bsA,
            const _Float16* __restrict__ Bm, int ldb, long long bsB,
            void* __restrict__ Cv, int ldc, long long bsC,
            const float* __restrict__ bias, int K)
{
    __shared__ __align__(16) unsigned char AsRaw[A_F32 ? 16384 : 8192]; // 128x32
    __shared__ __align__(16) unsigned char BsRaw[8192];                 // 128x32 f16

    const int tid  = threadIdx.x;
    const int lane = tid & 63;
    const int wave = tid >> 6;
    const int wm   = (wave >> 1) * 64;
    const int wn   = (wave & 1) * 64;
    const int fr   = lane & 15;
    const int fq   = lane >> 4;

    const int tm = blockIdx.y, tn = blockIdx.x, bz = blockIdx.z;
    const long long aRowBase = (long long)tm * 128;
    const long long bRowBase = (long long)tn * 128;
    const _Float16* Bbase = Bm + (long long)bz * bsB;

    floatx4 acc[4][4];
#pragma unroll
    for (int i = 0; i < 4; ++i)
#pragma unroll
        for (int j = 0; j < 4; ++j) acc[i][j] = (floatx4)0.0f;

    for (int k0 = 0; k0 < K; k0 += 32) {
        __syncthreads();

        if (A_F32) {
            const float* A1 = (const float*)A1v + (long long)bz * bsA;
            const float* A2 = (const float*)A2v;
#pragma unroll
            for (int is = 0; is < 4; ++is) {
                const int r  = (tid >> 3) + is * 32;
                const int ch = (tid & 7) ^ (r & 7);
                const int kk = k0 + ch * 4;
                const float* src = (kk < Ksplit)
                    ? A1 + (aRowBase + r) * lda1 + kk
                    : A2 + (aRowBase + r) * lda2 + (kk - Ksplit);
                llds16(src, AsRaw + tid * 16 + is * 4096);
            }
        } else {
            const _Float16* A1 = (const _Float16*)A1v + (long long)bz * bsA;
#pragma unroll
            for (int is = 0; is < 2; ++is) {
                const int r  = (tid >> 2) + is * 64;
                const int ch = (tid & 3) ^ (r & 3);
                llds16(A1 + (aRowBase + r) * lda1 + k0 + ch * 8,
                       AsRaw + tid * 16 + is * 4096);
            }
        }
#pragma unroll
        for (int is = 0; is < 2; ++is) {
            const int r  = (tid >> 2) + is * 64;
            const int ch = (tid & 3) ^ (r & 3);
            llds16(Bbase + (bRowBase + r) * ldb + k0 + ch * 8,
                   BsRaw + tid * 16 + is * 4096);
        }

        __syncthreads();

        half8 af[4], bf[4];
        if (A_F32) {
            const float* As32 = (const float*)AsRaw;
#pragma unroll
            for (int i = 0; i < 4; ++i) {
                const int r  = wm + i * 16 + fr;
                const int c0 = ((2 * fq) ^ (r & 7)) * 4;
                const int c1 = ((2 * fq + 1) ^ (r & 7)) * 4;
                floatx4 f0 = *(const floatx4*)(As32 + r * 32 + c0);
                floatx4 f1 = *(const floatx4*)(As32 + r * 32 + c1);
                half8 h;
#pragma unroll
                for (int j = 0; j < 4; ++j) {
                    h[j]     = (_Float16)f0[j];
                    h[4 + j] = (_Float16)f1[j];
                }
                af[i] = h;
            }
        } else {
            const _Float16* As16 = (const _Float16*)AsRaw;
#pragma unroll
            for (int i = 0; i < 4; ++i) {
                const int r  = wm + i * 16 + fr;
                const int ch = fq ^ (r & 3);
                af[i] = *(const half8*)(As16 + r * 32 + ch * 8);
            }
        }
        {
            const _Float16* Bs16 = (const _Float16*)BsRaw;
#pragma unroll
            for (int j = 0; j < 4; ++j) {
                const int r  = wn + j * 16 + fr;
                const int ch = fq ^ (r & 3);
                bf[j] = *(const half8*)(Bs16 + r * 32 + ch * 8);
            }
        }
#pragma unroll
        for (int i = 0; i < 4; ++i)
#pragma unroll
            for (int j = 0; j < 4; ++j)
                acc[i][j] = __builtin_amdgcn_mfma_f32_16x16x32_f16(af[i], bf[j], acc[i][j], 0, 0, 0);
    }

    const int crow0 = tm * 128 + wm + fq * 4;
    const int ccol0 = tn * 128 + wn + fr;
    if (OUT_F16) {
        _Float16* C = (_Float16*)Cv + (long long)bz * bsC;
#pragma unroll
        for (int i = 0; i < 4; ++i)
#pragma unroll
            for (int j = 0; j < 4; ++j) {
                const int col = ccol0 + j * 16;
                const float bv = bias[col];
#pragma unroll
                for (int r = 0; r < 4; ++r)
                    C[(long long)(crow0 + i*16 + r) * ldc + col] = (_Float16)(acc[i][j][r] + bv);
            }
    } else {
        float* C = (float*)Cv + (long long)bz * bsC;
#pragma unroll
        for (int i = 0; i < 4; ++i)
#pragma unroll
            for (int j = 0; j < 4; ++j) {
                const int col = ccol0 + j * 16;
#pragma unroll
                for (int r = 0; r < 4; ++r)
                    C[(long long)(crow0 + i*16 + r) * ldc + col] = acc[i][j][r];
            }
    }
}

// ---------------------------------------------------------------------------
// 256x256x(BK=64) f16 GEMM, 8-phase schedule. C = A[M][K] * B^T.
// Folded: z < zsplit uses (A0,B0,C0) batch z, else (A1,B1,C1) batch z-zsplit.
// OUT16: C written as f16 (score staging); else f32. grid (8, 8, 2*Bn).
// ---------------------------------------------------------------------------
template<bool OUT16>
__global__ __launch_bounds__(512, 2)
void gemm256_k(const _Float16* __restrict__ A0, const _Float16* __restrict__ A1,
               const _Float16* __restrict__ B0, const _Float16* __restrict__ B1,
               void* __restrict__ C0v, void* __restrict__ C1v,
               long long bsA, int lda, long long bsB, int ldb,
               long long bsC, int ldc, int K, int zsplit)
{
    __shared__ __align__(16) _Float16 lds[65536];   // 2 bufs x (A 16384 + B 16384)

    const int nwg  = 64 * gridDim.z;
    const int lin0 = (blockIdx.z * 8 + blockIdx.y) * 8 + blockIdx.x;
    const int cpx  = nwg >> 3;
    const int lin  = (lin0 & 7) * cpx + (lin0 >> 3);
    const int tn   = lin & 7;
    const int tm   = (lin >> 3) & 7;
    const int bz   = lin >> 6;

    const bool sel = (bz >= zsplit);
    const int  bzl = sel ? (bz - zsplit) : bz;
    const _Float16* Am = sel ? A1 : A0;
    const _Float16* Bm = sel ? B1 : B0;

    const int tid  = threadIdx.x;
    const int lane = tid & 63;
    const int wave = tid >> 6;          // 0..7
    const int wm   = (wave >> 2) * 128; // 0 / 128
    const int wn   = (wave & 3) * 64;   // 0,64,128,192
    const int fr   = lane & 15;
    const int fq   = lane >> 4;

    const _Float16* Ab = Am + (long long)bzl * bsA + (long long)tm * 256 * lda;
    const _Float16* Bb = Bm + (long long)bzl * bsB + (long long)tn * 256 * ldb;

    const int sr = lane >> 3;           // sub-row within an 8-row stripe
    const int ch = (lane & 7) ^ sr;     // swizzled source chunk (row&7 == sr)
    const _Float16* srcA[2][2];
    const _Float16* srcB[2][2];
#pragma unroll
    for (int h = 0; h < 2; ++h)
#pragma unroll
        for (int l = 0; l < 2; ++l) {
            const int r = h * 128 + (wave * 2 + l) * 8 + sr;   // tile row 0..255
            srcA[h][l] = Ab + (long long)r * lda + ch * 8;
            srcB[h][l] = Bb + (long long)r * ldb + ch * 8;
        }

    auto stageA = [&](int kt, int buf) {
#pragma unroll
        for (int h = 0; h < 2; ++h)
#pragma unroll
            for (int l = 0; l < 2; ++l)
                llds16(srcA[h][l] + kt * 64,
                       lds + buf * 32768 + h * 8192 + (wave * 2 + l) * 512 + lane * 8);
    };
    auto stageB = [&](int kt, int buf) {
#pragma unroll
        for (int h = 0; h < 2; ++h)
#pragma unroll
            for (int l = 0; l < 2; ++l)
                llds16(srcB[h][l] + kt * 64,
                       lds + buf * 32768 + 16384 + h * 8192 + (wave * 2 + l) * 512 + lane * 8);
    };

    auto rdA = [&](int buf, int im, int kk) -> half8 {
        const int row = wm + im * 16 + fr;
        const int c   = (kk * 4 + fq) ^ (row & 7);
        return *(const half8*)(lds + buf * 32768 + row * 64 + c * 8);
    };
    auto rdB = [&](int buf, int jn, int kk) -> half8 {
        const int row = wn + jn * 16 + fr;
        const int c   = (kk * 4 + fq) ^ (row & 7);
        return *(const half8*)(lds + buf * 32768 + 16384 + row * 64 + c * 8);
    };

    floatx4 acc[8][4];
#pragma unroll
    for (int i = 0; i < 8; ++i)
#pragma unroll
        for (int j = 0; j < 4; ++j) acc[i][j] = (floatx4)0.0f;

    const int KT = K >> 6;              // K-tiles of 64

    stageA(0, 0);
    stageB(0, 0);
    __syncthreads();                    // gate: tile 0 visible

    for (int kt = 0; kt < KT; ++kt) {
        const int buf = kt & 1;
        half8 af[4][2], bf[2][2];
#pragma unroll
        for (int q = 0; q < 4; ++q) {
            const int nh = q >> 1;                    // 0,0,1,1
            const int mh = (q == 1 || q == 2) ? 1 : 0; // snake: 0,1,1,0
            if (q == 0 || q == 2) {
#pragma unroll
                for (int j = 0; j < 2; ++j)
#pragma unroll
                    for (int kk = 0; kk < 2; ++kk)
                        bf[j][kk] = rdB(buf, nh * 2 + j, kk);
            }
            if (q != 2) {                             // q2 reuses q1's A half
#pragma unroll
                for (int i = 0; i < 4; ++i)
#pragma unroll
                    for (int kk = 0; kk < 2; ++kk)
                        af[i][kk] = rdA(buf, mh * 4 + i, kk);
            }
            if (kt + 1 < KT) {                        // prefetch next K-tile early
                if (q == 0)      stageA(kt + 1, buf ^ 1);
                else if (q == 1) stageB(kt + 1, buf ^ 1);
            }
            __builtin_amdgcn_s_barrier();
            __builtin_amdgcn_s_setprio(1);
#pragma unroll
            for (int i = 0; i < 4; ++i)
#pragma unroll
                for (int j = 0; j < 2; ++j)
#pragma unroll
                    for (int kk = 0; kk < 2; ++kk)
                        acc[mh * 4 + i][nh * 2 + j] =
                            __builtin_amdgcn_mfma_f32_16x16x32_f16(
                                af[i][kk], bf[j][kk], acc[mh * 4 + i][nh * 2 + j], 0, 0, 0);
            __builtin_amdgcn_s_setprio(0);
            if (q < 3) __builtin_amdgcn_s_barrier();
        }
        __syncthreads();   // gate: drains (3-phase-stale) prefetch, flips buffers
    }

    // D layout (16x16): col = lane&15, row = (lane>>4)*4 + r
    const int crow0 = tm * 256 + wm + fq * 4;
    const int ccol0 = tn * 256 + wn + fr;
    if (OUT16) {
        _Float16* Cb = (_Float16*)(sel ? C1v : C0v) + (long long)bzl * bsC;
#pragma unroll
        for (int i = 0; i < 8; ++i)
#pragma unroll
            for (int j = 0; j < 4; ++j) {
                const long long base = (long long)(crow0 + i * 16) * ldc + ccol0 + j * 16;
#pragma unroll
                for (int r = 0; r < 4; ++r)
                    Cb[base + (long long)r * ldc] = (_Float16)acc[i][j][r];
            }
    } else {
        float* Cb = (float*)(sel ? C1v : C0v) + (long long)bzl * bsC;
#pragma unroll
        for (int i = 0; i < 8; ++i)
#pragma unroll
            for (int j = 0; j < 4; ++j) {
                const long long base = (long long)(crow0 + i * 16) * ldc + ccol0 + j * 16;
#pragma unroll
                for (int r = 0; r < 4; ++r)
                    Cb[base + (long long)r * ldc] = acc[i][j][r];
            }
    }
}

// ---------------------------------------------------------------------------
// 256x128x(BK=64) f16 GEMM, same 4-subphase counted-prefetch schedule.
// Two pointer sets selected by blockIdx.z >= zsplit. Used for phase 4.
// ---------------------------------------------------------------------------
template<bool OUT_F16>
__global__ __launch_bounds__(512, 2)
void gemm256x128_k(const _Float16* __restrict__ A0, const _Float16* __restrict__ A1,
                   long long bsA, int lda,
                   const _Float16* __restrict__ B0, const _Float16* __restrict__ B1,
                   long long bsB, int ldb,
                   void* __restrict__ C0, void* __restrict__ C1,
                   long long bsC, int ldc,
                   const float* __restrict__ bias0, const float* __restrict__ bias1,
                   int K, int zsplit)
{
    __shared__ __align__(16) _Float16 lds[49152];   // 2 bufs x (A 16384 + B 8192)

    const int gx   = gridDim.x, gy = gridDim.y;
    const int nwg  = gx * gy * gridDim.z;
    const int lin0 = (blockIdx.z * gy + blockIdx.y) * gx + blockIdx.x;
    const int cpx  = nwg >> 3;
    const int lin  = (lin0 & 7) * cpx + (lin0 >> 3);
    const int tn   = lin % gx;
    const int tmp2 = lin / gx;
    const int tm   = tmp2 % gy;
    const int bz   = tmp2 / gy;

    const bool sel = (bz >= zsplit);
    const int  bzl = sel ? (bz - zsplit) : bz;
    const _Float16* Am = sel ? A1 : A0;
    const _Float16* Bm = sel ? B1 : B0;

    const int tid  = threadIdx.x;
    const int lane = tid & 63;
    const int wave = tid >> 6;          // 0..7
    const int wm   = (wave >> 2) * 128; // 0 / 128
    const int wn   = (wave & 3) * 32;   // 0,32,64,96
    const int fr   = lane & 15;
    const int fq   = lane >> 4;

    const _Float16* Ab = Am + (long long)bzl * bsA + (long long)tm * 256 * lda;
    const _Float16* Bb = Bm + (long long)bzl * bsB + (long long)tn * 128 * ldb;

    const int sr = lane >> 3;
    const int ch = (lane & 7) ^ sr;     // source-side swizzle (involution)
    const _Float16* srcA[2][2];
    const _Float16* srcB[2];
#pragma unroll
    for (int h = 0; h < 2; ++h)
#pragma unroll
        for (int l = 0; l < 2; ++l)
            srcA[h][l] = Ab + (long long)(h * 128 + (wave * 2 + l) * 8 + sr) * lda + ch * 8;
#pragma unroll
    for (int l = 0; l < 2; ++l)
        srcB[l] = Bb + (long long)((wave * 2 + l) * 8 + sr) * ldb + ch * 8;

    auto stageA = [&](int kt, int buf) {
#pragma unroll
        for (int h = 0; h < 2; ++h)
#pragma unroll
            for (int l = 0; l < 2; ++l)
                llds16(srcA[h][l] + kt * 64,
                       lds + buf * 24576 + h * 8192 + (wave * 2 + l) * 512 + lane * 8);
    };
    auto stageB = [&](int kt, int buf) {
#pragma unroll
        for (int l = 0; l < 2; ++l)
            llds16(srcB[l] + kt * 64,
                   lds + buf * 24576 + 16384 + (wave * 2 + l) * 512 + lane * 8);
    };

    auto rdA = [&](int buf, int im, int kk) -> half8 {
        const int row = wm + im * 16 + fr;
        const int c   = (kk * 4 + fq) ^ (row & 7);
        return *(const half8*)(lds + buf * 24576 + row * 64 + c * 8);
    };
    auto rdB = [&](int buf, int jn, int kk) -> half8 {
        const int row = wn + jn * 16 + fr;
        const int c   = (kk * 4 + fq) ^ (row & 7);
        return *(const half8*)(lds + buf * 24576 + 16384 + row * 64 + c * 8);
    };

    floatx4 acc[8][2];
#pragma unroll
    for (int i = 0; i < 8; ++i)
#pragma unroll
        for (int j = 0; j < 2; ++j) acc[i][j] = (floatx4)0.0f;

    const int KT = K >> 6;

    stageA(0, 0);
    stageB(0, 0);
    __syncthreads();

    for (int kt = 0; kt < KT; ++kt) {
        const int buf = kt & 1;
        half8 afA[4][2], afB[4][2], bf0[2], bf1[2];

#pragma unroll
        for (int kk = 0; kk < 2; ++kk) bf0[kk] = rdB(buf, 0, kk);
#pragma unroll
        for (int i = 0; i < 4; ++i)
#pragma unroll
            for (int kk = 0; kk < 2; ++kk) afA[i][kk] = rdA(buf, i, kk);
        if (kt + 1 < KT) stageA(kt + 1, buf ^ 1);
        __builtin_amdgcn_s_barrier();
        __builtin_amdgcn_s_setprio(1);
#pragma unroll
        for (int i = 0; i < 4; ++i)
#pragma unroll
            for (int kk = 0; kk < 2; ++kk)
                acc[i][0] = __builtin_amdgcn_mfma_f32_16x16x32_f16(afA[i][kk], bf0[kk], acc[i][0], 0, 0, 0);
        __builtin_amdgcn_s_setprio(0);
        __builtin_amdgcn_s_barrier();

#pragma unroll
        for (int i = 0; i < 4; ++i)
#pragma unroll
            for (int kk = 0; kk < 2; ++kk) afB[i][kk] = rdA(buf, 4 + i, kk);
        if (kt + 1 < KT) stageB(kt + 1, buf ^ 1);
        __builtin_amdgcn_s_barrier();
        __builtin_amdgcn_s_setprio(1);
#pragma unroll
        for (int i = 0; i < 4; ++i)
#pragma unroll
            for (int kk = 0; kk < 2; ++kk)
                acc[4 + i][0] = __builtin_amdgcn_mfma_f32_16x16x32_f16(afB[i][kk], bf0[kk], acc[4 + i][0], 0, 0, 0);
        __builtin_amdgcn_s_setprio(0);
        __builtin_amdgcn_s_barrier();

#pragma unroll
        for (int kk = 0; kk < 2; ++kk) bf1[kk] = rdB(buf, 1, kk);
        __builtin_amdgcn_s_barrier();
        __builtin_amdgcn_s_setprio(1);
#pragma unroll
        for (int i = 0; i < 4; ++i)
#pragma unroll
            for (int kk = 0; kk < 2; ++kk)
                acc[4 + i][1] = __builtin_amdgcn_mfma_f32_16x16x32_f16(afB[i][kk], bf1[kk], acc[4 + i][1], 0, 0, 0);
        __builtin_amdgcn_s_setprio(0);
        __builtin_amdgcn_s_barrier();

        __builtin_amdgcn_s_setprio(1);
#pragma unroll
        for (int i = 0; i < 4; ++i)
#pragma unroll
            for (int kk = 0; kk < 2; ++kk)
                acc[i][1] = __builtin_amdgcn_mfma_f32_16x16x32_f16(afA[i][kk], bf1[kk], acc[i][1], 0, 0, 0);
        __builtin_amdgcn_s_setprio(0);

        __syncthreads();
    }

    const int crow0 = tm * 256 + wm + fq * 4;
    const int ccol0 = tn * 128 + wn + fr;
    if (OUT_F16) {
        const float* bias = sel ? bias1 : bias0;
        _Float16* C = (_Float16*)(sel ? C1 : C0) + (long long)bzl * bsC;
#pragma unroll
        for (int i = 0; i < 8; ++i)
#pragma unroll
            for (int j = 0; j < 2; ++j) {
                const int col = ccol0 + j * 16;
                const float bv = bias[col];
#pragma unroll
                for (int r = 0; r < 4; ++r)
                    C[(long long)(crow0 + i * 16 + r) * ldc + col] = (_Float16)(acc[i][j][r] + bv);
            }
    } else {
        float* C = (float*)(sel ? C1 : C0) + (long long)bzl * bsC;
#pragma unroll
        for (int i = 0; i < 8; ++i)
#pragma unroll
            for (int j = 0; j < 2; ++j) {
                const int col = ccol0 + j * 16;
#pragma unroll
                for (int r = 0; r < 4; ++r)
                    C[(long long)(crow0 + i * 16 + r) * ldc + col] = acc[i][j][r];
            }
    }
}

// ---------------------------------------------------------------------------
// All four projections in ONE launch. Same 256x128 schedule as above.
// grid (4, 64, 4): z = 0: cat1*WTk1->k1p, 1: cat2*WTk2->k2p,
//                  2: cat1*WTpk1->pk1,   3: cat2*WTpk2->pk2.
// K = 512 (z<2) / 768 (z>=2); A = cat (lda=768, k-proj reads first 512 cols).
// f16 out + bias.
// ---------------------------------------------------------------------------
__global__ __launch_bounds__(512, 2)
void gemm_proj_k(const _Float16* __restrict__ Acat1, const _Float16* __restrict__ Acat2,
                 const _Float16* __restrict__ B0, const _Float16* __restrict__ B1,
                 const _Float16* __restrict__ B2, const _Float16* __restrict__ B3,
                 _Float16* __restrict__ C0, _Float16* __restrict__ C1,
                 _Float16* __restrict__ C2, _Float16* __restrict__ C3,
                 const float* __restrict__ bias0, const float* __restrict__ bias1,
                 const float* __restrict__ bias2, const float* __restrict__ bias3,
                 int K0, int K1)
{
    __shared__ __align__(16) _Float16 lds[49152];

    const int nwg  = 4 * 64 * 4;
    const int lin0 = (blockIdx.z * 64 + blockIdx.y) * 4 + blockIdx.x;
    const int cpx  = nwg >> 3;
    const int lin  = (lin0 & 7) * cpx + (lin0 >> 3);
    const int tn   = lin & 3;
    const int tm   = (lin >> 2) & 63;
    const int pz   = lin >> 8;          // 0..3

    const _Float16* Am = (pz & 1) ? Acat2 : Acat1;
    const _Float16* Bm; _Float16* Cm; const float* bias; int K;
    if      (pz == 0) { Bm = B0; Cm = C0; bias = bias0; K = K0; }
    else if (pz == 1) { Bm = B1; Cm = C1; bias = bias1; K = K0; }
    else if (pz == 2) { Bm = B2; Cm = C2; bias = bias2; K = K1; }
    else              { Bm = B3; Cm = C3; bias = bias3; K = K1; }
    const int lda = KD + PKD;           // cat leading dim
    const int ldb = K;                  // WT is [AD][K]
    const int ldc = AD;

    const int tid  = threadIdx.x;
    const int lane = tid & 63;
    const int wave = tid >> 6;
    const int wm   = (wave >> 2) * 128;
    const int wn   = (wave & 3) * 32;
    const int fr   = lane & 15;
    const int fq   = lane >> 4;

    const _Float16* Ab = Am + (long long)tm * 256 * lda;
    const _Float16* Bb = Bm + (long long)tn * 128 * ldb;

    const int sr = lane >> 3;
    const int ch = (lane & 7) ^ sr;
    const _Float16* srcA[2][2];
    const _Float16* srcB[2];
#pragma unroll
    for (int h = 0; h < 2; ++h)
#pragma unroll
        for (int l = 0; l < 2; ++l)
            srcA[h][l] = Ab + (long long)(h * 128 + (wave * 2 + l) * 8 + sr) * lda + ch * 8;
#pragma unroll
    for (int l = 0; l < 2; ++l)
        srcB[l] = Bb + (long long)((wave * 2 + l) * 8 + sr) * ldb + ch * 8;

    auto stageA = [&](int kt, int buf) {
#pragma unroll
        for (int h = 0; h < 2; ++h)
#pragma unroll
            for (int l = 0; l < 2; ++l)
                llds16(srcA[h][l] + kt * 64,
                       lds + buf * 24576 + h * 8192 + (wave * 2 + l) * 512 + lane * 8);
    };
    auto stageB = [&](int kt, int buf) {
#pragma unroll
        for (int l = 0; l < 2; ++l)
            llds16(srcB[l] + kt * 64,
                   lds + buf * 24576 + 16384 + (wave * 2 + l) * 512 + lane * 8);
    };

    auto rdA = [&](int buf, int im, int kk) -> half8 {
        const int row = wm + im * 16 + fr;
        const int c   = (kk * 4 + fq) ^ (row & 7);
        return *(const half8*)(lds + buf * 24576 + row * 64 + c * 8);
    };
    auto rdB = [&](int buf, int jn, int kk) -> half8 {
        const int row = wn + jn * 16 + fr;
        const int c   = (kk * 4 + fq) ^ (row & 7);
        return *(const half8*)(lds + buf * 24576 + 16384 + row * 64 + c * 8);
    };

    floatx4 acc[8][2];
#pragma unroll
    for (int i = 0; i < 8; ++i)
#pragma unroll
        for (int j = 0; j < 2; ++j) acc[i][j] = (floatx4)0.0f;

    const int KT = K >> 6;

    stageA(0, 0);
    stageB(0, 0);
    __syncthreads();

    for (int kt = 0; kt < KT; ++kt) {
        const int buf = kt & 1;
        half8 afA[4][2], afB[4][2], bf0[2], bf1[2];

#pragma unroll
        for (int kk = 0; kk < 2; ++kk) bf0[kk] = rdB(buf, 0, kk);
#pragma unroll
        for (int i = 0; i < 4; ++i)
#pragma unroll
            for (int kk = 0; kk < 2; ++kk) afA[i][kk] = rdA(buf, i, kk);
        if (kt + 1 < KT) stageA(kt + 1, buf ^ 1);
        __builtin_amdgcn_s_barrier();
        __builtin_amdgcn_s_setprio(1);
#pragma unroll
        for (int i = 0; i < 4; ++i)
#pragma unroll
            for (int kk = 0; kk < 2; ++kk)
                acc[i][0] = __builtin_amdgcn_mfma_f32_16x16x32_f16(afA[i][kk], bf0[kk], acc[i][0], 0, 0, 0);
        __builtin_amdgcn_s_setprio(0);
        __builtin_amdgcn_s_barrier();

#pragma unroll
        for (int i = 0; i < 4; ++i)
#pragma unroll
            for (int kk = 0; kk < 2; ++kk) afB[i][kk] = rdA(buf, 4 + i, kk);
        if (kt + 1 < KT) stageB(kt + 1, buf ^ 1);
        __builtin_amdgcn_s_barrier();
        __builtin_amdgcn_s_setprio(1);
#pragma unroll
        for (int i = 0; i < 4; ++i)
#pragma unroll
            for (int kk = 0; kk < 2; ++kk)
                acc[4 + i][0] = __builtin_amdgcn_mfma_f32_16x16x32_f16(afB[i][kk], bf0[kk], acc[4 + i][0], 0, 0, 0);
        __builtin_amdgcn_s_setprio(0);
        __builtin_amdgcn_s_barrier();

#pragma unroll
        for (int kk = 0; kk < 2; ++kk) bf1[kk] = rdB(buf, 1, kk);
        __builtin_amdgcn_s_barrier();
        __builtin_amdgcn_s_setprio(1);
#pragma unroll
        for (int i = 0; i < 4; ++i)
#pragma unroll
            for (int kk = 0; kk < 2; ++kk)
                acc[4 + i][1] = __builtin_amdgcn_mfma_f32_16x16x32_f16(afB[i][kk], bf1[kk], acc[4 + i][1], 0, 0, 0);
        __builtin_amdgcn_s_setprio(0);
        __builtin_amdgcn_s_barrier();

        __builtin_amdgcn_s_setprio(1);
#pragma unroll
        for (int i = 0; i < 4; ++i)
#pragma unroll
            for (int kk = 0; kk < 2; ++kk)
                acc[i][1] = __builtin_amdgcn_mfma_f32_16x16x32_f16(afA[i][kk], bf1[kk], acc[i][1], 0, 0, 0);
        __builtin_amdgcn_s_setprio(0);

        __syncthreads();
    }

    const int crow0 = tm * 256 + wm + fq * 4;
    const int ccol0 = tn * 128 + wn + fr;
#pragma unroll
    for (int i = 0; i < 8; ++i)
#pragma unroll
        for (int j = 0; j < 2; ++j) {
            const int col = ccol0 + j * 16;
            const float bv = bias[col];
#pragma unroll
            for (int r = 0; r < 4; ++r)
                Cm[(long long)(crow0 + i * 16 + r) * ldc + col] = (_Float16)(acc[i][j][r] + bv);
        }
}

// ---------------------------------------------------------------------------
__device__ __forceinline__ int load_len(const int* __restrict__ p, int b)
{
    return (p[1] == 0) ? p[2 * b] : p[b];
}

// ---------------------------------------------------------------------------
// Masked softmax, both sides in one launch (z: 0 = w1 side, 1 = w2 side).
// F16IN: read f16 scores from wh, write f32 w + f16 wh (in place).
// else:  read f32 w in place,  write f32 w (+ f16 wh if non-null).
// Mask: (r>=lenR[b]) XOR (c>=lenC[b]).
// ---------------------------------------------------------------------------
template<bool F16IN>
__global__ __launch_bounds__(256)
void softmax_mask_k(float* __restrict__ w1p, float* __restrict__ w2p,
                    _Float16* __restrict__ wh1, _Float16* __restrict__ wh2,
                    const int* __restrict__ len1, const int* __restrict__ len2)
{
    const int z = blockIdx.z;
    float* w = z ? w2p : w1p;
    _Float16* wh = z ? wh2 : wh1;
    const int* lenR = z ? len1 : len2;
    const int* lenC = z ? len2 : len1;

    const int b = blockIdx.y;
    const int r = blockIdx.x;
    const long long rowOff = ((long long)b * Sq + r) * (long long)Sq;
    float* row = w + rowOff;
    const int lr = load_len(lenR, b);
    const int lc = load_len(lenC, b);
    const bool rover = (r >= lr);
    const int tid  = threadIdx.x;
    const int lane = tid & 63;
    const int wave = tid >> 6;

    float v[8];
    if (F16IN) {
        const half8 hv = *(const half8*)(wh + rowOff + tid * 8);
#pragma unroll
        for (int j = 0; j < 8; ++j) v[j] = (float)hv[j];
    } else {
        const floatx4 x0 = *(const floatx4*)(row + tid * 8);
        const floatx4 x1 = *(const floatx4*)(row + tid * 8 + 4);
#pragma unroll
        for (int j = 0; j < 4; ++j) { v[j] = x0[j]; v[4 + j] = x1[j]; }
    }

    float m = -3.0e38f;
#pragma unroll
    for (int j = 0; j < 8; ++j) {
        const int c = tid * 8 + j;
        if (rover != (c >= lc)) v[j] = -__builtin_inff();
        m = fmaxf(m, v[j]);
    }
#pragma unroll
    for (int off = 32; off > 0; off >>= 1) m = fmaxf(m, __shfl_xor(m, off, 64));
    __shared__ float redm[4], reds[4];
    if (lane == 0) redm[wave] = m;
    __syncthreads();
    m = fmaxf(fmaxf(redm[0], redm[1]), fmaxf(redm[2], redm[3]));

    float s = 0.f;
#pragma unroll
    for (int j = 0; j < 8; ++j) { v[j] = __expf(v[j] - m); s += v[j]; }
#pragma unroll
    for (int off = 32; off > 0; off >>= 1) s += __shfl_xor(s, off, 64);
    if (lane == 0) reds[wave] = s;
    __syncthreads();
    s = reds[0] + reds[1] + reds[2] + reds[3];
    const float inv = 1.0f / s;   // row never fully masked (lengths in [S/2,S))

    floatx4 x0, x1;
#pragma unroll
    for (int j = 0; j < 4; ++j) { x0[j] = v[j] * inv; x1[j] = v[4 + j] * inv; }
    *(floatx4*)(row + tid * 8)     = x0;
    *(floatx4*)(row + tid * 8 + 4) = x1;
    if (F16IN || wh != nullptr) {
        half8 h;
#pragma unroll
        for (int j = 0; j < 4; ++j) { h[j] = (_Float16)x0[j]; h[4 + j] = (_Float16)x1[j]; }
        *(half8*)(wh + rowOff + tid * 8) = h;
    }
}

// ---------------------------------------------------------------------------
extern "C" void kernel_launch(void* const* d_in, const int* in_sizes, int n_in,
                              void* d_out, int out_size, void* d_ws, size_t ws_size,
                              hipStream_t stream)
{
    (void)in_sizes; (void)n_in; (void)out_size;
    const float* k1    = (const float*)d_in[0];
    const float* k2    = (const float*)d_in[1];
    const float* pk1in = (const float*)d_in[2];
    const float* pk2in = (const float*)d_in[3];
    const float* v1    = (const float*)d_in[4];
    const float* v2    = (const float*)d_in[5];
    const float* W_k1  = (const float*)d_in[6];
    const float* b_k1  = (const float*)d_in[7];
    const float* W_k2  = (const float*)d_in[8];
    const float* b_k2  = (const float*)d_in[9];
    const float* W_pk1 = (const float*)d_in[10];
    const float* b_pk1 = (const float*)d_in[11];
    const float* W_pk2 = (const float*)d_in[12];
    const float* b_pk2 = (const float*)d_in[13];
    const int* len1 = (const int*)d_in[14];
    const int* len2 = (const int*)d_in[15];

    float* out = (float*)d_out;
    float* o1 = out;                                  // [Bn,Sq,DV]
    float* o2 = o1 + (long long)Bn * Sq * DV;         // [Bn,Sq,DV]
    float* w1 = o2 + (long long)Bn * Sq * DV;         // [Bn,Sq,Sq]
    float* w2 = w1 + (long long)Bn * Sq * Sq;         // [Bn,Sq,Sq]

    // fp16 intermediates live in the (dead until phase 4) o1/o2 regions.
    _Float16* k1p = (_Float16*)o1;                    // [Bn*Sq][AD]
    _Float16* k2p = k1p + (long long)Bn * Sq * AD;
    _Float16* pk1 = (_Float16*)o2;
    _Float16* pk2 = pk1 + (long long)Bn * Sq * AD;
    _Float16* cat1 = pk2 + (long long)Bn * Sq * AD;   // [Bn*Sq][KD+PKD] f16
    _Float16* cat2 = cat1 + (long long)Bn * Sq * (KD + PKD);

    _Float16* vT1   = (_Float16*)d_ws;                // [Bn][DV][Sq]
    _Float16* vT2   = vT1 + (long long)Bn * DV * Sq;
    _Float16* WTk1  = vT2 + (long long)Bn * DV * Sq;  // [AD][KD]
    _Float16* WTk2  = WTk1 + AD * KD;
    _Float16* WTpk1 = WTk2 + AD * KD;                 // [AD][KD+PKD]
    _Float16* WTpk2 = WTpk1 + AD * (KD + PKD);

    const unsigned long long fixedHalves =
        2ull * Bn * DV * Sq + 2ull * AD * KD + 2ull * AD * (KD + PKD);
    _Float16* w1h = (_Float16*)d_ws + fixedHalves;    // [Bn][Sq][Sq] f16
    _Float16* w2h = w1h + (long long)Bn * Sq * Sq;
    const bool fast =
        ws_size >= (fixedHalves + 2ull * Bn * Sq * Sq) * sizeof(_Float16);

    // ---- phase 0: weight transposes (1), v transposes (1), concat-casts (1)
    wT_all_k<<<dim3(AD/32, (KD+PKD)/32, 4), 256, 0, stream>>>(
        W_k1, W_k2, W_pk1, W_pk2, WTk1, WTk2, WTpk1, WTpk2);
    transpose_cast_k<<<dim3(DV/32, Sq/32, 2*Bn), 256, 0, stream>>>(
        v1, v2, vT1, vT2, Sq, DV, (long long)Sq*DV, (long long)Sq*DV, Bn);
    cast_cat_k<<<dim3((Bn*Sq*(KD+PKD))/(256*8), 1, 2), 256, 0, stream>>>(
        k1, pk1in, cat1, k2, pk2in, cat2);

    // ---- phase 1: all four projections in one launch ----
    gemm_proj_k<<<dim3(AD/128, (Bn*Sq)/256, 4), 512, 0, stream>>>(
        cat1, cat2,
        WTk1, WTk2, WTpk1, WTpk2,
        k1p, k2p, pk1, pk2,
        b_k1, b_k2, b_pk1, b_pk2,
        KD, KD + PKD);

    // ---- phase 2: both score GEMMs in one launch ----
    if (fast) {
        gemm256_k<true><<<dim3(Sq/256, Sq/256, 2*Bn), 512, 0, stream>>>(
            pk2, pk1, k1p, k2p, w1h, w2h,
            (long long)Sq*AD, AD, (long long)Sq*AD, AD,
            (long long)Sq*Sq, Sq, AD, Bn);
    } else {
        gemm256_k<false><<<dim3(Sq/256, Sq/256, 2*Bn), 512, 0, stream>>>(
            pk2, pk1, k1p, k2p, w1, w2,
            (long long)Sq*AD, AD, (long long)Sq*AD, AD,
            (long long)Sq*Sq, Sq, AD, Bn);
    }

    // ---- phase 3: masked softmax, both sides in one launch ----
    if (fast) {
        softmax_mask_k<true><<<dim3(Sq, Bn, 2), 256, 0, stream>>>(
            w1, w2, w1h, w2h, len1, len2);
    } else {
        softmax_mask_k<false><<<dim3(Sq, Bn, 2), 256, 0, stream>>>(
            w1, w2, nullptr, nullptr, len1, len2);
    }

    // ---- phase 4: o = w @ v (one launch, z = 16) ----
    if (fast) {
        gemm256x128_k<false><<<dim3(DV/128, Sq/256, 2*Bn), 512, 0, stream>>>(
            w1h, w2h, (long long)Sq*Sq, Sq,
            vT1, vT2, (long long)DV*Sq, Sq,
            o1, o2, (long long)Sq*DV, DV,
            nullptr, nullptr, Sq, Bn);
    } else {
        const dim3 gOut(DV/128, Sq/128, Bn);
        gemm_k<true, false><<<gOut, 256, 0, stream>>>(
            w1, w1, Sq, Sq, Sq, (long long)Sq*Sq,
            vT1, Sq, (long long)DV*Sq,
            o1, DV, (long long)Sq*DV, nullptr, Sq);
        gemm_k<true, false><<<gOut, 256, 0, stream>>>(
            w2, w2, Sq, Sq, Sq, (long long)Sq*Sq,
            vT2, Sq, (long long)DV*Sq,
            o2, DV, (long long)Sq*DV, nullptr, Sq);
    }
}

// Round 4
// 767.785 us; speedup vs baseline: 1.2147x; 1.0316x over previous
//
#include <hip/hip_runtime.h>

typedef _Float16 half8 __attribute__((ext_vector_type(8)));
typedef float    floatx4 __attribute__((ext_vector_type(4)));
typedef unsigned short u16;

constexpr int Bn  = 8;
constexpr int Sq  = 2048;   // S1 == S2
constexpr int KD  = 512;    // K1_DIM == K2_DIM
constexpr int PKD = 256;
constexpr int AD  = 512;    // ATT_DIM
constexpr int DV  = 512;

// 16-byte async global->LDS DMA. LDS dest must be wave-uniform base + lane*16.
__device__ __forceinline__ void llds16(const void* g, void* l)
{
    __builtin_amdgcn_global_load_lds(
        (const __attribute__((address_space(1))) unsigned int*)g,
        (__attribute__((address_space(3))) unsigned int*)l, 16, 0, 0);
}

// ---------------------------------------------------------------------------
// transpose + cast f32 -> f16 (dual-source fold): out[j][i] = (f16) in[i][j]
// ---------------------------------------------------------------------------
__global__ __launch_bounds__(256)
void transpose_cast_k(const float* __restrict__ in0, const float* __restrict__ in1,
                      _Float16* __restrict__ out0, _Float16* __restrict__ out1,
                      int inRows, int inCols, long long bsIn, long long bsOut,
                      int zsplit)
{
    __shared__ float t[32][33];
    const int bz = blockIdx.z;
    const bool sel = (bz >= zsplit);
    const int b = sel ? bz - zsplit : bz;
    const float* in = (sel ? in1 : in0) + (long long)b * bsIn;
    _Float16* out = (sel ? out1 : out0) + (long long)b * bsOut;
    const int tx = threadIdx.x & 31;
    const int ty = threadIdx.x >> 5;     // 0..7
    const int c0 = blockIdx.x * 32;
    const int r0 = blockIdx.y * 32;
#pragma unroll
    for (int i = 0; i < 4; ++i)
        t[ty + 8*i][tx] = in[(long long)(r0 + ty + 8*i) * inCols + c0 + tx];
    __syncthreads();
#pragma unroll
    for (int i = 0; i < 4; ++i)
        out[(long long)(c0 + ty + 8*i) * inRows + r0 + tx] = (_Float16)t[tx][ty + 8*i];
}

// ---------------------------------------------------------------------------
// All four weight transposes in one launch. WT[n][k] = (f16) W[k][n].
// ---------------------------------------------------------------------------
__global__ __launch_bounds__(256)
void wT_all_k(const float* __restrict__ Wk1, const float* __restrict__ Wk2,
              const float* __restrict__ Wpk1, const float* __restrict__ Wpk2,
              _Float16* __restrict__ Tk1, _Float16* __restrict__ Tk2,
              _Float16* __restrict__ Tpk1, _Float16* __restrict__ Tpk2)
{
    const int z = blockIdx.z;
    const float* W; _Float16* T; int Krows;
    if      (z == 0) { W = Wk1;  T = Tk1;  Krows = KD; }
    else if (z == 1) { W = Wk2;  T = Tk2;  Krows = KD; }
    else if (z == 2) { W = Wpk1; T = Tpk1; Krows = KD + PKD; }
    else             { W = Wpk2; T = Tpk2; Krows = KD + PKD; }
    const int r0 = blockIdx.y * 32;          // k index
    if (r0 >= Krows) return;
    const int c0 = blockIdx.x * 32;          // n index (AD)
    __shared__ float t[32][33];
    const int tx = threadIdx.x & 31;
    const int ty = threadIdx.x >> 5;
#pragma unroll
    for (int i = 0; i < 4; ++i)
        t[ty + 8*i][tx] = W[(long long)(r0 + ty + 8*i) * AD + c0 + tx];
    __syncthreads();
#pragma unroll
    for (int i = 0; i < 4; ++i)
        T[(long long)(c0 + ty + 8*i) * Krows + r0 + tx] = (_Float16)t[tx][ty + 8*i];
}

// ---------------------------------------------------------------------------
// cast+concat f32 -> f16 (both sides): out[r][0..511]=x, out[r][512..767]=y.
// ---------------------------------------------------------------------------
__global__ __launch_bounds__(256)
void cast_cat_k(const float* __restrict__ x0, const float* __restrict__ y0,
                _Float16* __restrict__ o0,
                const float* __restrict__ x1, const float* __restrict__ y1,
                _Float16* __restrict__ o1)
{
    const bool sel = (blockIdx.z != 0);
    const float* x = sel ? x1 : x0;
    const float* y = sel ? y1 : y0;
    _Float16* out = sel ? o1 : o0;
    const int idx = blockIdx.x * 256 + threadIdx.x;
    const int e   = idx * 8;                 // < 16384*768 = 12.6M, fits int
    const int r   = e / 768;
    const int c   = e % 768;
    const float* src = (c < 512) ? (x + (long long)r * 512 + c)
                                 : (y + (long long)r * 256 + (c - 512));
    const floatx4 f0 = *(const floatx4*)(src);
    const floatx4 f1 = *(const floatx4*)(src + 4);
    half8 h;
#pragma unroll
    for (int j = 0; j < 4; ++j) { h[j] = (_Float16)f0[j]; h[4 + j] = (_Float16)f1[j]; }
    *(half8*)(out + (long long)e) = h;
}

// ---------------------------------------------------------------------------
// 128x128x32 fp16 MFMA GEMM (m97-style). Retained only for the !fast
// fallback (phase 4 reading f32 w).
// ---------------------------------------------------------------------------
template<bool A_F32, bool OUT_F16>
__global__ __launch_bounds__(256, 2)
void gemm_k(const void* __restrict__ A1v, const void* __restrict__ A2v, int Ksplit,
            int lda1, int lda2, long long bsA,
            const _Float16* __restrict__ Bm, int ldb, long long bsB,
            void* __restrict__ Cv, int ldc, long long bsC,
            const float* __restrict__ bias, int K)
{
    __shared__ __align__(16) unsigned char AsRaw[A_F32 ? 16384 : 8192]; // 128x32
    __shared__ __align__(16) unsigned char BsRaw[8192];                 // 128x32 f16

    const int tid  = threadIdx.x;
    const int lane = tid & 63;
    const int wave = tid >> 6;
    const int wm   = (wave >> 1) * 64;
    const int wn   = (wave & 1) * 64;
    const int fr   = lane & 15;
    const int fq   = lane >> 4;

    const int tm = blockIdx.y, tn = blockIdx.x, bz = blockIdx.z;
    const long long aRowBase = (long long)tm * 128;
    const long long bRowBase = (long long)tn * 128;
    const _Float16* Bbase = Bm + (long long)bz * bsB;

    floatx4 acc[4][4];
#pragma unroll
    for (int i = 0; i < 4; ++i)
#pragma unroll
        for (int j = 0; j < 4; ++j) acc[i][j] = (floatx4)0.0f;

    for (int k0 = 0; k0 < K; k0 += 32) {
        __syncthreads();

        if (A_F32) {
            const float* A1 = (const float*)A1v + (long long)bz * bsA;
            const float* A2 = (const float*)A2v;
#pragma unroll
            for (int is = 0; is < 4; ++is) {
                const int r  = (tid >> 3) + is * 32;
                const int ch = (tid & 7) ^ (r & 7);
                const int kk = k0 + ch * 4;
                const float* src = (kk < Ksplit)
                    ? A1 + (aRowBase + r) * lda1 + kk
                    : A2 + (aRowBase + r) * lda2 + (kk - Ksplit);
                llds16(src, AsRaw + tid * 16 + is * 4096);
            }
        } else {
            const _Float16* A1 = (const _Float16*)A1v + (long long)bz * bsA;
#pragma unroll
            for (int is = 0; is < 2; ++is) {
                const int r  = (tid >> 2) + is * 64;
                const int ch = (tid & 3) ^ (r & 3);
                llds16(A1 + (aRowBase + r) * lda1 + k0 + ch * 8,
                       AsRaw + tid * 16 + is * 4096);
            }
        }
#pragma unroll
        for (int is = 0; is < 2; ++is) {
            const int r  = (tid >> 2) + is * 64;
            const int ch = (tid & 3) ^ (r & 3);
            llds16(Bbase + (bRowBase + r) * ldb + k0 + ch * 8,
                   BsRaw + tid * 16 + is * 4096);
        }

        __syncthreads();

        half8 af[4], bf[4];
        if (A_F32) {
            const float* As32 = (const float*)AsRaw;
#pragma unroll
            for (int i = 0; i < 4; ++i) {
                const int r  = wm + i * 16 + fr;
                const int c0 = ((2 * fq) ^ (r & 7)) * 4;
                const int c1 = ((2 * fq + 1) ^ (r & 7)) * 4;
                floatx4 f0 = *(const floatx4*)(As32 + r * 32 + c0);
                floatx4 f1 = *(const floatx4*)(As32 + r * 32 + c1);
                half8 h;
#pragma unroll
                for (int j = 0; j < 4; ++j) {
                    h[j]     = (_Float16)f0[j];
                    h[4 + j] = (_Float16)f1[j];
                }
                af[i] = h;
            }
        } else {
            const _Float16* As16 = (const _Float16*)AsRaw;
#pragma unroll
            for (int i = 0; i < 4; ++i) {
                const int r  = wm + i * 16 + fr;
                const int ch = fq ^ (r & 3);
                af[i] = *(const half8*)(As16 + r * 32 + ch * 8);
            }
        }
        {
            const _Float16* Bs16 = (const _Float16*)BsRaw;
#pragma unroll
            for (int j = 0; j < 4; ++j) {
                const int r  = wn + j * 16 + fr;
                const int ch = fq ^ (r & 3);
                bf[j] = *(const half8*)(Bs16 + r * 32 + ch * 8);
            }
        }
#pragma unroll
        for (int i = 0; i < 4; ++i)
#pragma unroll
            for (int j = 0; j < 4; ++j)
                acc[i][j] = __builtin_amdgcn_mfma_f32_16x16x32_f16(af[i], bf[j], acc[i][j], 0, 0, 0);
    }

    const int crow0 = tm * 128 + wm + fq * 4;
    const int ccol0 = tn * 128 + wn + fr;
    if (OUT_F16) {
        _Float16* C = (_Float16*)Cv + (long long)bz * bsC;
#pragma unroll
        for (int i = 0; i < 4; ++i)
#pragma unroll
            for (int j = 0; j < 4; ++j) {
                const int col = ccol0 + j * 16;
                const float bv = bias[col];
#pragma unroll
                for (int r = 0; r < 4; ++r)
                    C[(long long)(crow0 + i*16 + r) * ldc + col] = (_Float16)(acc[i][j][r] + bv);
            }
    } else {
        float* C = (float*)Cv + (long long)bz * bsC;
#pragma unroll
        for (int i = 0; i < 4; ++i)
#pragma unroll
            for (int j = 0; j < 4; ++j) {
                const int col = ccol0 + j * 16;
#pragma unroll
                for (int r = 0; r < 4; ++r)
                    C[(long long)(crow0 + i*16 + r) * ldc + col] = acc[i][j][r];
            }
    }
}

// ---------------------------------------------------------------------------
// 256x256x(BK=64) f16 GEMM, 8-phase schedule. C = A[M][K] * B^T.
// Folded: z < zsplit uses (A0,B0,C0) batch z, else (A1,B1,C1) batch z-zsplit.
// OUT16: C written as f16 (score staging); else f32. grid (8, 8, 2*Bn).
// (phase 2 — unchanged, proven; operands are L3-resident so the per-tile
//  vmcnt(0) drain at __syncthreads is cheap here.)
// ---------------------------------------------------------------------------
template<bool OUT16>
__global__ __launch_bounds__(512, 2)
void gemm256_k(const _Float16* __restrict__ A0, const _Float16* __restrict__ A1,
               const _Float16* __restrict__ B0, const _Float16* __restrict__ B1,
               void* __restrict__ C0v, void* __restrict__ C1v,
               long long bsA, int lda, long long bsB, int ldb,
               long long bsC, int ldc, int K, int zsplit)
{
    __shared__ __align__(16) _Float16 lds[65536];   // 2 bufs x (A 16384 + B 16384)

    const int nwg  = 64 * gridDim.z;
    const int lin0 = (blockIdx.z * 8 + blockIdx.y) * 8 + blockIdx.x;
    const int cpx  = nwg >> 3;
    const int lin  = (lin0 & 7) * cpx + (lin0 >> 3);
    const int tn   = lin & 7;
    const int tm   = (lin >> 3) & 7;
    const int bz   = lin >> 6;

    const bool sel = (bz >= zsplit);
    const int  bzl = sel ? (bz - zsplit) : bz;
    const _Float16* Am = sel ? A1 : A0;
    const _Float16* Bm = sel ? B1 : B0;

    const int tid  = threadIdx.x;
    const int lane = tid & 63;
    const int wave = tid >> 6;          // 0..7
    const int wm   = (wave >> 2) * 128; // 0 / 128
    const int wn   = (wave & 3) * 64;   // 0,64,128,192
    const int fr   = lane & 15;
    const int fq   = lane >> 4;

    const _Float16* Ab = Am + (long long)bzl * bsA + (long long)tm * 256 * lda;
    const _Float16* Bb = Bm + (long long)bzl * bsB + (long long)tn * 256 * ldb;

    const int sr = lane >> 3;           // sub-row within an 8-row stripe
    const int ch = (lane & 7) ^ sr;     // swizzled source chunk (row&7 == sr)
    const _Float16* srcA[2][2];
    const _Float16* srcB[2][2];
#pragma unroll
    for (int h = 0; h < 2; ++h)
#pragma unroll
        for (int l = 0; l < 2; ++l) {
            const int r = h * 128 + (wave * 2 + l) * 8 + sr;   // tile row 0..255
            srcA[h][l] = Ab + (long long)r * lda + ch * 8;
            srcB[h][l] = Bb + (long long)r * ldb + ch * 8;
        }

    auto stageA = [&](int kt, int buf) {
#pragma unroll
        for (int h = 0; h < 2; ++h)
#pragma unroll
            for (int l = 0; l < 2; ++l)
                llds16(srcA[h][l] + kt * 64,
                       lds + buf * 32768 + h * 8192 + (wave * 2 + l) * 512 + lane * 8);
    };
    auto stageB = [&](int kt, int buf) {
#pragma unroll
        for (int h = 0; h < 2; ++h)
#pragma unroll
            for (int l = 0; l < 2; ++l)
                llds16(srcB[h][l] + kt * 64,
                       lds + buf * 32768 + 16384 + h * 8192 + (wave * 2 + l) * 512 + lane * 8);
    };

    auto rdA = [&](int buf, int im, int kk) -> half8 {
        const int row = wm + im * 16 + fr;
        const int c   = (kk * 4 + fq) ^ (row & 7);
        return *(const half8*)(lds + buf * 32768 + row * 64 + c * 8);
    };
    auto rdB = [&](int buf, int jn, int kk) -> half8 {
        const int row = wn + jn * 16 + fr;
        const int c   = (kk * 4 + fq) ^ (row & 7);
        return *(const half8*)(lds + buf * 32768 + 16384 + row * 64 + c * 8);
    };

    floatx4 acc[8][4];
#pragma unroll
    for (int i = 0; i < 8; ++i)
#pragma unroll
        for (int j = 0; j < 4; ++j) acc[i][j] = (floatx4)0.0f;

    const int KT = K >> 6;              // K-tiles of 64

    stageA(0, 0);
    stageB(0, 0);
    __syncthreads();                    // gate: tile 0 visible

    for (int kt = 0; kt < KT; ++kt) {
        const int buf = kt & 1;
        half8 af[4][2], bf[2][2];
#pragma unroll
        for (int q = 0; q < 4; ++q) {
            const int nh = q >> 1;                    // 0,0,1,1
            const int mh = (q == 1 || q == 2) ? 1 : 0; // snake: 0,1,1,0
            if (q == 0 || q == 2) {
#pragma unroll
                for (int j = 0; j < 2; ++j)
#pragma unroll
                    for (int kk = 0; kk < 2; ++kk)
                        bf[j][kk] = rdB(buf, nh * 2 + j, kk);
            }
            if (q != 2) {                             // q2 reuses q1's A half
#pragma unroll
                for (int i = 0; i < 4; ++i)
#pragma unroll
                    for (int kk = 0; kk < 2; ++kk)
                        af[i][kk] = rdA(buf, mh * 4 + i, kk);
            }
            if (kt + 1 < KT) {                        // prefetch next K-tile early
                if (q == 0)      stageA(kt + 1, buf ^ 1);
                else if (q == 1) stageB(kt + 1, buf ^ 1);
            }
            __builtin_amdgcn_s_barrier();
            __builtin_amdgcn_s_setprio(1);
#pragma unroll
            for (int i = 0; i < 4; ++i)
#pragma unroll
                for (int j = 0; j < 2; ++j)
#pragma unroll
                    for (int kk = 0; kk < 2; ++kk)
                        acc[mh * 4 + i][nh * 2 + j] =
                            __builtin_amdgcn_mfma_f32_16x16x32_f16(
                                af[i][kk], bf[j][kk], acc[mh * 4 + i][nh * 2 + j], 0, 0, 0);
            __builtin_amdgcn_s_setprio(0);
            if (q < 3) __builtin_amdgcn_s_barrier();
        }
        __syncthreads();   // gate: flips buffers
    }

    // D layout (16x16): col = lane&15, row = (lane>>4)*4 + r
    const int crow0 = tm * 256 + wm + fq * 4;
    const int ccol0 = tn * 256 + wn + fr;
    if (OUT16) {
        _Float16* Cb = (_Float16*)(sel ? C1v : C0v) + (long long)bzl * bsC;
#pragma unroll
        for (int i = 0; i < 8; ++i)
#pragma unroll
            for (int j = 0; j < 4; ++j) {
                const long long base = (long long)(crow0 + i * 16) * ldc + ccol0 + j * 16;
#pragma unroll
                for (int r = 0; r < 4; ++r)
                    Cb[base + (long long)r * ldc] = (_Float16)acc[i][j][r];
            }
    } else {
        float* Cb = (float*)(sel ? C1v : C0v) + (long long)bzl * bsC;
#pragma unroll
        for (int i = 0; i < 8; ++i)
#pragma unroll
            for (int j = 0; j < 4; ++j) {
                const long long base = (long long)(crow0 + i * 16) * ldc + ccol0 + j * 16;
#pragma unroll
                for (int r = 0; r < 4; ++r)
                    Cb[base + (long long)r * ldc] = acc[i][j][r];
            }
    }
}

// ---------------------------------------------------------------------------
// 256x128x(BK=64) f16 GEMM, 4-subphase schedule, 3-BUFFER depth-2 prefetch
// with counted vmcnt (T3/T4): during kt we issue kt+2's loads (A at q0, B at
// q1; 6 llds16/thread/tile); the kt-boundary waits vmcnt(6) (oldest 6 = tile
// kt+1 retired => next buffer complete) + s_barrier -- never vmcnt(0) in the
// main loop. Slot being DMA'd (kt+2)%3 != slot read (kt)%3 != pending (kt+1)%3.
// LDS 3 x 48 KiB = 144 KiB (1 block/CU). Accumulation order unchanged.
// ---------------------------------------------------------------------------
template<bool OUT_F16>
__global__ __launch_bounds__(512, 2)
void gemm256x128_k(const _Float16* __restrict__ A0, const _Float16* __restrict__ A1,
                   long long bsA, int lda,
                   const _Float16* __restrict__ B0, const _Float16* __restrict__ B1,
                   long long bsB, int ldb,
                   void* __restrict__ C0, void* __restrict__ C1,
                   long long bsC, int ldc,
                   const float* __restrict__ bias0, const float* __restrict__ bias1,
                   int K, int zsplit)
{
    __shared__ __align__(16) _Float16 lds[73728];   // 3 bufs x (A 16384 + B 8192)

    const int gx   = gridDim.x, gy = gridDim.y;
    const int nwg  = gx * gy * gridDim.z;
    const int lin0 = (blockIdx.z * gy + blockIdx.y) * gx + blockIdx.x;
    const int cpx  = nwg >> 3;
    const int lin  = (lin0 & 7) * cpx + (lin0 >> 3);
    const int tn   = lin % gx;
    const int tmp2 = lin / gx;
    const int tm   = tmp2 % gy;
    const int bz   = tmp2 / gy;

    const bool sel = (bz >= zsplit);
    const int  bzl = sel ? (bz - zsplit) : bz;
    const _Float16* Am = sel ? A1 : A0;
    const _Float16* Bm = sel ? B1 : B0;

    const int tid  = threadIdx.x;
    const int lane = tid & 63;
    const int wave = tid >> 6;          // 0..7
    const int wm   = (wave >> 2) * 128; // 0 / 128
    const int wn   = (wave & 3) * 32;   // 0,32,64,96
    const int fr   = lane & 15;
    const int fq   = lane >> 4;

    const _Float16* Ab = Am + (long long)bzl * bsA + (long long)tm * 256 * lda;
    const _Float16* Bb = Bm + (long long)bzl * bsB + (long long)tn * 128 * ldb;

    const int sr = lane >> 3;
    const int ch = (lane & 7) ^ sr;     // source-side swizzle (involution)
    const _Float16* srcA[2][2];
    const _Float16* srcB[2];
#pragma unroll
    for (int h = 0; h < 2; ++h)
#pragma unroll
        for (int l = 0; l < 2; ++l)
            srcA[h][l] = Ab + (long long)(h * 128 + (wave * 2 + l) * 8 + sr) * lda + ch * 8;
#pragma unroll
    for (int l = 0; l < 2; ++l)
        srcB[l] = Bb + (long long)((wave * 2 + l) * 8 + sr) * ldb + ch * 8;

    auto stageA = [&](int kt, int buf) {
#pragma unroll
        for (int h = 0; h < 2; ++h)
#pragma unroll
            for (int l = 0; l < 2; ++l)
                llds16(srcA[h][l] + kt * 64,
                       lds + buf * 24576 + h * 8192 + (wave * 2 + l) * 512 + lane * 8);
    };
    auto stageB = [&](int kt, int buf) {
#pragma unroll
        for (int l = 0; l < 2; ++l)
            llds16(srcB[l] + kt * 64,
                   lds + buf * 24576 + 16384 + (wave * 2 + l) * 512 + lane * 8);
    };

    auto rdA = [&](int buf, int im, int kk) -> half8 {
        const int row = wm + im * 16 + fr;
        const int c   = (kk * 4 + fq) ^ (row & 7);
        return *(const half8*)(lds + buf * 24576 + row * 64 + c * 8);
    };
    auto rdB = [&](int buf, int jn, int kk) -> half8 {
        const int row = wn + jn * 16 + fr;
        const int c   = (kk * 4 + fq) ^ (row & 7);
        return *(const half8*)(lds + buf * 24576 + 16384 + row * 64 + c * 8);
    };

    floatx4 acc[8][2];
#pragma unroll
    for (int i = 0; i < 8; ++i)
#pragma unroll
        for (int j = 0; j < 2; ++j) acc[i][j] = (floatx4)0.0f;

    const int KT = K >> 6;

    // prologue: stage tiles 0 and 1; wait only for tile 0 (6 newest in flight)
    stageA(0, 0); stageB(0, 0);
    if (KT > 1) {
        stageA(1, 1); stageB(1, 1);
        asm volatile("s_waitcnt vmcnt(6)" ::: "memory");
    } else {
        asm volatile("s_waitcnt vmcnt(0)" ::: "memory");
    }
    __builtin_amdgcn_sched_barrier(0);
    __builtin_amdgcn_s_barrier();
    __builtin_amdgcn_sched_barrier(0);

    int bufR = 0, bufP = 2;             // read slot (kt%3), prefetch slot ((kt+2)%3)
    for (int kt = 0; kt < KT; ++kt) {
        half8 afA[4][2], afB[4][2], bf0[2], bf1[2];
        const bool pf = (kt + 2 < KT);

        // q0: n0 frags + A low half; prefetch next-next A; MFMA m0 x n0
#pragma unroll
        for (int kk = 0; kk < 2; ++kk) bf0[kk] = rdB(bufR, 0, kk);
#pragma unroll
        for (int i = 0; i < 4; ++i)
#pragma unroll
            for (int kk = 0; kk < 2; ++kk) afA[i][kk] = rdA(bufR, i, kk);
        if (pf) stageA(kt + 2, bufP);
        __builtin_amdgcn_s_barrier();
        __builtin_amdgcn_s_setprio(1);
#pragma unroll
        for (int i = 0; i < 4; ++i)
#pragma unroll
            for (int kk = 0; kk < 2; ++kk)
                acc[i][0] = __builtin_amdgcn_mfma_f32_16x16x32_f16(afA[i][kk], bf0[kk], acc[i][0], 0, 0, 0);
        __builtin_amdgcn_s_setprio(0);
        __builtin_amdgcn_s_barrier();

        // q1: A high half; prefetch next-next B; MFMA m1 x n0
#pragma unroll
        for (int i = 0; i < 4; ++i)
#pragma unroll
            for (int kk = 0; kk < 2; ++kk) afB[i][kk] = rdA(bufR, 4 + i, kk);
        if (pf) stageB(kt + 2, bufP);
        __builtin_amdgcn_s_barrier();
        __builtin_amdgcn_s_setprio(1);
#pragma unroll
        for (int i = 0; i < 4; ++i)
#pragma unroll
            for (int kk = 0; kk < 2; ++kk)
                acc[4 + i][0] = __builtin_amdgcn_mfma_f32_16x16x32_f16(afB[i][kk], bf0[kk], acc[4 + i][0], 0, 0, 0);
        __builtin_amdgcn_s_setprio(0);
        __builtin_amdgcn_s_barrier();

        // q2: n1 frags; MFMA m1 x n1 (reuse afB)
#pragma unroll
        for (int kk = 0; kk < 2; ++kk) bf1[kk] = rdB(bufR, 1, kk);
        __builtin_amdgcn_s_barrier();
        __builtin_amdgcn_s_setprio(1);
#pragma unroll
        for (int i = 0; i < 4; ++i)
#pragma unroll
            for (int kk = 0; kk < 2; ++kk)
                acc[4 + i][1] = __builtin_amdgcn_mfma_f32_16x16x32_f16(afB[i][kk], bf1[kk], acc[4 + i][1], 0, 0, 0);
        __builtin_amdgcn_s_setprio(0);
        __builtin_amdgcn_s_barrier();

        // q3: MFMA m0 x n1 (reuse afA, bf1); no loads
        __builtin_amdgcn_s_setprio(1);
#pragma unroll
        for (int i = 0; i < 4; ++i)
#pragma unroll
            for (int kk = 0; kk < 2; ++kk)
                acc[i][1] = __builtin_amdgcn_mfma_f32_16x16x32_f16(afA[i][kk], bf1[kk], acc[i][1], 0, 0, 0);
        __builtin_amdgcn_s_setprio(0);

        // kt boundary: counted wait (never drain-to-0 while prefetch pending)
        if (kt + 1 < KT) {
            if (pf) asm volatile("s_waitcnt vmcnt(6)" ::: "memory");
            else    asm volatile("s_waitcnt vmcnt(0)" ::: "memory");
            __builtin_amdgcn_sched_barrier(0);
            __builtin_amdgcn_s_barrier();
            __builtin_amdgcn_sched_barrier(0);
        }
        bufR = (bufR == 2) ? 0 : bufR + 1;
        bufP = (bufP == 2) ? 0 : bufP + 1;
    }

    const int crow0 = tm * 256 + wm + fq * 4;
    const int ccol0 = tn * 128 + wn + fr;
    if (OUT_F16) {
        const float* bias = sel ? bias1 : bias0;
        _Float16* C = (_Float16*)(sel ? C1 : C0) + (long long)bzl * bsC;
#pragma unroll
        for (int i = 0; i < 8; ++i)
#pragma unroll
            for (int j = 0; j < 2; ++j) {
                const int col = ccol0 + j * 16;
                const float bv = bias[col];
#pragma unroll
                for (int r = 0; r < 4; ++r)
                    C[(long long)(crow0 + i * 16 + r) * ldc + col] = (_Float16)(acc[i][j][r] + bv);
            }
    } else {
        float* C = (float*)(sel ? C1 : C0) + (long long)bzl * bsC;
#pragma unroll
        for (int i = 0; i < 8; ++i)
#pragma unroll
            for (int j = 0; j < 2; ++j) {
                const int col = ccol0 + j * 16;
#pragma unroll
                for (int r = 0; r < 4; ++r)
                    C[(long long)(crow0 + i * 16 + r) * ldc + col] = acc[i][j][r];
            }
    }
}

// ---------------------------------------------------------------------------
// All four projections in ONE launch, same 3-buffer counted-vmcnt schedule.
// grid (4, 64, 4): pz = 0: cat1*WTk1->k1p, 1: cat2*WTk2->k2p,
//                  2: cat1*WTpk1->pk1,    3: cat2*WTpk2->pk2.
// ---------------------------------------------------------------------------
__global__ __launch_bounds__(512, 2)
void gemm_proj_k(const _Float16* __restrict__ Acat1, const _Float16* __restrict__ Acat2,
                 const _Float16* __restrict__ B0, const _Float16* __restrict__ B1,
                 const _Float16* __restrict__ B2, const _Float16* __restrict__ B3,
                 _Float16* __restrict__ C0, _Float16* __restrict__ C1,
                 _Float16* __restrict__ C2, _Float16* __restrict__ C3,
                 const float* __restrict__ bias0, const float* __restrict__ bias1,
                 const float* __restrict__ bias2, const float* __restrict__ bias3,
                 int K0, int K1)
{
    __shared__ __align__(16) _Float16 lds[73728];   // 3 bufs x 24576

    const int nwg  = 4 * 64 * 4;
    const int lin0 = (blockIdx.z * 64 + blockIdx.y) * 4 + blockIdx.x;
    const int cpx  = nwg >> 3;
    const int lin  = (lin0 & 7) * cpx + (lin0 >> 3);
    const int tn   = lin & 3;
    const int tm   = (lin >> 2) & 63;
    const int pz   = lin >> 8;          // 0..3

    const _Float16* Am = (pz & 1) ? Acat2 : Acat1;
    const _Float16* Bm; _Float16* Cm; const float* bias; int K;
    if      (pz == 0) { Bm = B0; Cm = C0; bias = bias0; K = K0; }
    else if (pz == 1) { Bm = B1; Cm = C1; bias = bias1; K = K0; }
    else if (pz == 2) { Bm = B2; Cm = C2; bias = bias2; K = K1; }
    else              { Bm = B3; Cm = C3; bias = bias3; K = K1; }
    const int lda = KD + PKD;           // cat leading dim
    const int ldb = K;                  // WT is [AD][K]
    const int ldc = AD;

    const int tid  = threadIdx.x;
    const int lane = tid & 63;
    const int wave = tid >> 6;
    const int wm   = (wave >> 2) * 128;
    const int wn   = (wave & 3) * 32;
    const int fr   = lane & 15;
    const int fq   = lane >> 4;

    const _Float16* Ab = Am + (long long)tm * 256 * lda;
    const _Float16* Bb = Bm + (long long)tn * 128 * ldb;

    const int sr = lane >> 3;
    const int ch = (lane & 7) ^ sr;
    const _Float16* srcA[2][2];
    const _Float16* srcB[2];
#pragma unroll
    for (int h = 0; h < 2; ++h)
#pragma unroll
        for (int l = 0; l < 2; ++l)
            srcA[h][l] = Ab + (long long)(h * 128 + (wave * 2 + l) * 8 + sr) * lda + ch * 8;
#pragma unroll
    for (int l = 0; l < 2; ++l)
        srcB[l] = Bb + (long long)((wave * 2 + l) * 8 + sr) * ldb + ch * 8;

    auto stageA = [&](int kt, int buf) {
#pragma unroll
        for (int h = 0; h < 2; ++h)
#pragma unroll
            for (int l = 0; l < 2; ++l)
                llds16(srcA[h][l] + kt * 64,
                       lds + buf * 24576 + h * 8192 + (wave * 2 + l) * 512 + lane * 8);
    };
    auto stageB = [&](int kt, int buf) {
#pragma unroll
        for (int l = 0; l < 2; ++l)
            llds16(srcB[l] + kt * 64,
                   lds + buf * 24576 + 16384 + (wave * 2 + l) * 512 + lane * 8);
    };

    auto rdA = [&](int buf, int im, int kk) -> half8 {
        const int row = wm + im * 16 + fr;
        const int c   = (kk * 4 + fq) ^ (row & 7);
        return *(const half8*)(lds + buf * 24576 + row * 64 + c * 8);
    };
    auto rdB = [&](int buf, int jn, int kk) -> half8 {
        const int row = wn + jn * 16 + fr;
        const int c   = (kk * 4 + fq) ^ (row & 7);
        return *(const half8*)(lds + buf * 24576 + 16384 + row * 64 + c * 8);
    };

    floatx4 acc[8][2];
#pragma unroll
    for (int i = 0; i < 8; ++i)
#pragma unroll
        for (int j = 0; j < 2; ++j) acc[i][j] = (floatx4)0.0f;

    const int KT = K >> 6;

    stageA(0, 0); stageB(0, 0);
    if (KT > 1) {
        stageA(1, 1); stageB(1, 1);
        asm volatile("s_waitcnt vmcnt(6)" ::: "memory");
    } else {
        asm volatile("s_waitcnt vmcnt(0)" ::: "memory");
    }
    __builtin_amdgcn_sched_barrier(0);
    __builtin_amdgcn_s_barrier();
    __builtin_amdgcn_sched_barrier(0);

    int bufR = 0, bufP = 2;
    for (int kt = 0; kt < KT; ++kt) {
        half8 afA[4][2], afB[4][2], bf0[2], bf1[2];
        const bool pf = (kt + 2 < KT);

#pragma unroll
        for (int kk = 0; kk < 2; ++kk) bf0[kk] = rdB(bufR, 0, kk);
#pragma unroll
        for (int i = 0; i < 4; ++i)
#pragma unroll
            for (int kk = 0; kk < 2; ++kk) afA[i][kk] = rdA(bufR, i, kk);
        if (pf) stageA(kt + 2, bufP);
        __builtin_amdgcn_s_barrier();
        __builtin_amdgcn_s_setprio(1);
#pragma unroll
        for (int i = 0; i < 4; ++i)
#pragma unroll
            for (int kk = 0; kk < 2; ++kk)
                acc[i][0] = __builtin_amdgcn_mfma_f32_16x16x32_f16(afA[i][kk], bf0[kk], acc[i][0], 0, 0, 0);
        __builtin_amdgcn_s_setprio(0);
        __builtin_amdgcn_s_barrier();

#pragma unroll
        for (int i = 0; i < 4; ++i)
#pragma unroll
            for (int kk = 0; kk < 2; ++kk) afB[i][kk] = rdA(bufR, 4 + i, kk);
        if (pf) stageB(kt + 2, bufP);
        __builtin_amdgcn_s_barrier();
        __builtin_amdgcn_s_setprio(1);
#pragma unroll
        for (int i = 0; i < 4; ++i)
#pragma unroll
            for (int kk = 0; kk < 2; ++kk)
                acc[4 + i][0] = __builtin_amdgcn_mfma_f32_16x16x32_f16(afB[i][kk], bf0[kk], acc[4 + i][0], 0, 0, 0);
        __builtin_amdgcn_s_setprio(0);
        __builtin_amdgcn_s_barrier();

#pragma unroll
        for (int kk = 0; kk < 2; ++kk) bf1[kk] = rdB(bufR, 1, kk);
        __builtin_amdgcn_s_barrier();
        __builtin_amdgcn_s_setprio(1);
#pragma unroll
        for (int i = 0; i < 4; ++i)
#pragma unroll
            for (int kk = 0; kk < 2; ++kk)
                acc[4 + i][1] = __builtin_amdgcn_mfma_f32_16x16x32_f16(afB[i][kk], bf1[kk], acc[4 + i][1], 0, 0, 0);
        __builtin_amdgcn_s_setprio(0);
        __builtin_amdgcn_s_barrier();

        __builtin_amdgcn_s_setprio(1);
#pragma unroll
        for (int i = 0; i < 4; ++i)
#pragma unroll
            for (int kk = 0; kk < 2; ++kk)
                acc[i][1] = __builtin_amdgcn_mfma_f32_16x16x32_f16(afA[i][kk], bf1[kk], acc[i][1], 0, 0, 0);
        __builtin_amdgcn_s_setprio(0);

        if (kt + 1 < KT) {
            if (pf) asm volatile("s_waitcnt vmcnt(6)" ::: "memory");
            else    asm volatile("s_waitcnt vmcnt(0)" ::: "memory");
            __builtin_amdgcn_sched_barrier(0);
            __builtin_amdgcn_s_barrier();
            __builtin_amdgcn_sched_barrier(0);
        }
        bufR = (bufR == 2) ? 0 : bufR + 1;
        bufP = (bufP == 2) ? 0 : bufP + 1;
    }

    const int crow0 = tm * 256 + wm + fq * 4;
    const int ccol0 = tn * 128 + wn + fr;
#pragma unroll
    for (int i = 0; i < 8; ++i)
#pragma unroll
        for (int j = 0; j < 2; ++j) {
            const int col = ccol0 + j * 16;
            const float bv = bias[col];
#pragma unroll
            for (int r = 0; r < 4; ++r)
                Cm[(long long)(crow0 + i * 16 + r) * ldc + col] = (_Float16)(acc[i][j][r] + bv);
        }
}

// ---------------------------------------------------------------------------
__device__ __forceinline__ int load_len(const int* __restrict__ p, int b)
{
    return (p[1] == 0) ? p[2 * b] : p[b];
}

// ---------------------------------------------------------------------------
// Masked softmax, both sides in one launch (z: 0 = w1 side, 1 = w2 side).
// F16IN: read f16 scores from wh, write f32 w + f16 wh (in place).
// ---------------------------------------------------------------------------
template<bool F16IN>
__global__ __launch_bounds__(256)
void softmax_mask_k(float* __restrict__ w1p, float* __restrict__ w2p,
                    _Float16* __restrict__ wh1, _Float16* __restrict__ wh2,
                    const int* __restrict__ len1, const int* __restrict__ len2)
{
    const int z = blockIdx.z;
    float* w = z ? w2p : w1p;
    _Float16* wh = z ? wh2 : wh1;
    const int* lenR = z ? len1 : len2;
    const int* lenC = z ? len2 : len1;

    const int b = blockIdx.y;
    const int r = blockIdx.x;
    const long long rowOff = ((long long)b * Sq + r) * (long long)Sq;
    float* row = w + rowOff;
    const int lr = load_len(lenR, b);
    const int lc = load_len(lenC, b);
    const bool rover = (r >= lr);
    const int tid  = threadIdx.x;
    const int lane = tid & 63;
    const int wave = tid >> 6;

    float v[8];
    if (F16IN) {
        const half8 hv = *(const half8*)(wh + rowOff + tid * 8);
#pragma unroll
        for (int j = 0; j < 8; ++j) v[j] = (float)hv[j];
    } else {
        const floatx4 x0 = *(const floatx4*)(row + tid * 8);
        const floatx4 x1 = *(const floatx4*)(row + tid * 8 + 4);
#pragma unroll
        for (int j = 0; j < 4; ++j) { v[j] = x0[j]; v[4 + j] = x1[j]; }
    }

    float m = -3.0e38f;
#pragma unroll
    for (int j = 0; j < 8; ++j) {
        const int c = tid * 8 + j;
        if (rover != (c >= lc)) v[j] = -__builtin_inff();
        m = fmaxf(m, v[j]);
    }
#pragma unroll
    for (int off = 32; off > 0; off >>= 1) m = fmaxf(m, __shfl_xor(m, off, 64));
    __shared__ float redm[4], reds[4];
    if (lane == 0) redm[wave] = m;
    __syncthreads();
    m = fmaxf(fmaxf(redm[0], redm[1]), fmaxf(redm[2], redm[3]));

    float s = 0.f;
#pragma unroll
    for (int j = 0; j < 8; ++j) { v[j] = __expf(v[j] - m); s += v[j]; }
#pragma unroll
    for (int off = 32; off > 0; off >>= 1) s += __shfl_xor(s, off, 64);
    if (lane == 0) reds[wave] = s;
    __syncthreads();
    s = reds[0] + reds[1] + reds[2] + reds[3];
    const float inv = 1.0f / s;   // row never fully masked (lengths in [S/2,S))

    floatx4 x0, x1;
#pragma unroll
    for (int j = 0; j < 4; ++j) { x0[j] = v[j] * inv; x1[j] = v[4 + j] * inv; }
    *(floatx4*)(row + tid * 8)     = x0;
    *(floatx4*)(row + tid * 8 + 4) = x1;
    if (F16IN || wh != nullptr) {
        half8 h;
#pragma unroll
        for (int j = 0; j < 4; ++j) { h[j] = (_Float16)x0[j]; h[4 + j] = (_Float16)x1[j]; }
        *(half8*)(wh + rowOff + tid * 8) = h;
    }
}

// ---------------------------------------------------------------------------
extern "C" void kernel_launch(void* const* d_in, const int* in_sizes, int n_in,
                              void* d_out, int out_size, void* d_ws, size_t ws_size,
                              hipStream_t stream)
{
    (void)in_sizes; (void)n_in; (void)out_size;
    const float* k1    = (const float*)d_in[0];
    const float* k2    = (const float*)d_in[1];
    const float* pk1in = (const float*)d_in[2];
    const float* pk2in = (const float*)d_in[3];
    const float* v1    = (const float*)d_in[4];
    const float* v2    = (const float*)d_in[5];
    const float* W_k1  = (const float*)d_in[6];
    const float* b_k1  = (const float*)d_in[7];
    const float* W_k2  = (const float*)d_in[8];
    const float* b_k2  = (const float*)d_in[9];
    const float* W_pk1 = (const float*)d_in[10];
    const float* b_pk1 = (const float*)d_in[11];
    const float* W_pk2 = (const float*)d_in[12];
    const float* b_pk2 = (const float*)d_in[13];
    const int* len1 = (const int*)d_in[14];
    const int* len2 = (const int*)d_in[15];

    float* out = (float*)d_out;
    float* o1 = out;                                  // [Bn,Sq,DV]
    float* o2 = o1 + (long long)Bn * Sq * DV;         // [Bn,Sq,DV]
    float* w1 = o2 + (long long)Bn * Sq * DV;         // [Bn,Sq,Sq]
    float* w2 = w1 + (long long)Bn * Sq * Sq;         // [Bn,Sq,Sq]

    // fp16 intermediates live in the (dead until phase 4) o1/o2 regions.
    _Float16* k1p = (_Float16*)o1;                    // [Bn*Sq][AD]
    _Float16* k2p = k1p + (long long)Bn * Sq * AD;
    _Float16* pk1 = (_Float16*)o2;
    _Float16* pk2 = pk1 + (long long)Bn * Sq * AD;
    _Float16* cat1 = pk2 + (long long)Bn * Sq * AD;   // [Bn*Sq][KD+PKD] f16
    _Float16* cat2 = cat1 + (long long)Bn * Sq * (KD + PKD);

    _Float16* vT1   = (_Float16*)d_ws;                // [Bn][DV][Sq]
    _Float16* vT2   = vT1 + (long long)Bn * DV * Sq;
    _Float16* WTk1  = vT2 + (long long)Bn * DV * Sq;  // [AD][KD]
    _Float16* WTk2  = WTk1 + AD * KD;
    _Float16* WTpk1 = WTk2 + AD * KD;                 // [AD][KD+PKD]
    _Float16* WTpk2 = WTpk1 + AD * (KD + PKD);

    const unsigned long long fixedHalves =
        2ull * Bn * DV * Sq + 2ull * AD * KD + 2ull * AD * (KD + PKD);
    _Float16* w1h = (_Float16*)d_ws + fixedHalves;    // [Bn][Sq][Sq] f16
    _Float16* w2h = w1h + (long long)Bn * Sq * Sq;
    const bool fast =
        ws_size >= (fixedHalves + 2ull * Bn * Sq * Sq) * sizeof(_Float16);

    // ---- phase 0: weight transposes (1), v transposes (1), concat-casts (1)
    wT_all_k<<<dim3(AD/32, (KD+PKD)/32, 4), 256, 0, stream>>>(
        W_k1, W_k2, W_pk1, W_pk2, WTk1, WTk2, WTpk1, WTpk2);
    transpose_cast_k<<<dim3(DV/32, Sq/32, 2*Bn), 256, 0, stream>>>(
        v1, v2, vT1, vT2, Sq, DV, (long long)Sq*DV, (long long)Sq*DV, Bn);
    cast_cat_k<<<dim3((Bn*Sq*(KD+PKD))/(256*8), 1, 2), 256, 0, stream>>>(
        k1, pk1in, cat1, k2, pk2in, cat2);

    // ---- phase 1: all four projections in one launch ----
    gemm_proj_k<<<dim3(AD/128, (Bn*Sq)/256, 4), 512, 0, stream>>>(
        cat1, cat2,
        WTk1, WTk2, WTpk1, WTpk2,
        k1p, k2p, pk1, pk2,
        b_k1, b_k2, b_pk1, b_pk2,
        KD, KD + PKD);

    // ---- phase 2: both score GEMMs in one launch ----
    if (fast) {
        gemm256_k<true><<<dim3(Sq/256, Sq/256, 2*Bn), 512, 0, stream>>>(
            pk2, pk1, k1p, k2p, w1h, w2h,
            (long long)Sq*AD, AD, (long long)Sq*AD, AD,
            (long long)Sq*Sq, Sq, AD, Bn);
    } else {
        gemm256_k<false><<<dim3(Sq/256, Sq/256, 2*Bn), 512, 0, stream>>>(
            pk2, pk1, k1p, k2p, w1, w2,
            (long long)Sq*AD, AD, (long long)Sq*AD, AD,
            (long long)Sq*Sq, Sq, AD, Bn);
    }

    // ---- phase 3: masked softmax, both sides in one launch ----
    if (fast) {
        softmax_mask_k<true><<<dim3(Sq, Bn, 2), 256, 0, stream>>>(
            w1, w2, w1h, w2h, len1, len2);
    } else {
        softmax_mask_k<false><<<dim3(Sq, Bn, 2), 256, 0, stream>>>(
            w1, w2, nullptr, nullptr, len1, len2);
    }

    // ---- phase 4: o = w @ v (one launch, z = 16) ----
    if (fast) {
        gemm256x128_k<false><<<dim3(DV/128, Sq/256, 2*Bn), 512, 0, stream>>>(
            w1h, w2h, (long long)Sq*Sq, Sq,
            vT1, vT2, (long long)DV*Sq, Sq,
            o1, o2, (long long)Sq*DV, DV,
            nullptr, nullptr, Sq, Bn);
    } else {
        const dim3 gOut(DV/128, Sq/128, Bn);
        gemm_k<true, false><<<gOut, 256, 0, stream>>>(
            w1, w1, Sq, Sq, Sq, (long long)Sq*Sq,
            vT1, Sq, (long long)DV*Sq,
            o1, DV, (long long)Sq*DV, nullptr, Sq);
        gemm_k<true, false><<<gOut, 256, 0, stream>>>(
            w2, w2, Sq, Sq, Sq, (long long)Sq*Sq,
            vT2, Sq, (long long)DV*Sq,
            o2, DV, (long long)Sq*DV, nullptr, Sq);
    }
}